// Round 1
// baseline (1460.211 us; speedup 1.0000x reference)
//
#include <hip/hip_runtime.h>

#define N_NODES 100000
#define N_EDGES 3200000
#define HDIM 64
#define NGRAPH 512
#define NCLASS 6
#define BN_EPS 1e-5f

// ---------------- CSR build ----------------

__global__ void k_hist_edges(const int* __restrict__ dst, int* __restrict__ deg) {
    int e = blockIdx.x * blockDim.x + threadIdx.x;
    if (e < N_EDGES) atomicAdd(&deg[dst[e]], 1);
}

__global__ void k_hist_batch(const int* __restrict__ batch, int* __restrict__ gcnt) {
    int i = blockIdx.x * blockDim.x + threadIdx.x;
    if (i < N_NODES) atomicAdd(&gcnt[batch[i]], 1);
}

// 256 threads, 1024 elements per block
__global__ void k_scan1(const int* __restrict__ deg, int* __restrict__ tmp,
                        int* __restrict__ bsums) {
    __shared__ int sh[256];
    int t = threadIdx.x;
    int base = blockIdx.x * 1024 + t * 4;
    int v0 = (base + 0 < N_NODES) ? deg[base + 0] : 0;
    int v1 = (base + 1 < N_NODES) ? deg[base + 1] : 0;
    int v2 = (base + 2 < N_NODES) ? deg[base + 2] : 0;
    int v3 = (base + 3 < N_NODES) ? deg[base + 3] : 0;
    int p1 = v0, p2 = v0 + v1, p3 = v0 + v1 + v2;
    int tot = p3 + v3;
    sh[t] = tot;
    __syncthreads();
    for (int off = 1; off < 256; off <<= 1) {
        int x = (t >= off) ? sh[t - off] : 0;
        __syncthreads();
        sh[t] += x;
        __syncthreads();
    }
    int excl = sh[t] - tot;
    if (base + 0 < N_NODES) tmp[base + 0] = excl;
    if (base + 1 < N_NODES) tmp[base + 1] = excl + p1;
    if (base + 2 < N_NODES) tmp[base + 2] = excl + p2;
    if (base + 3 < N_NODES) tmp[base + 3] = excl + p3;
    if (t == 255) bsums[blockIdx.x] = sh[255];
}

__global__ void k_scan2(const int* __restrict__ bsums, int* __restrict__ boff, int nb) {
    __shared__ int sh[128];
    int t = threadIdx.x;
    int v = (t < nb) ? bsums[t] : 0;
    sh[t] = v;
    __syncthreads();
    for (int off = 1; off < 128; off <<= 1) {
        int x = (t >= off) ? sh[t - off] : 0;
        __syncthreads();
        sh[t] += x;
        __syncthreads();
    }
    if (t < nb) boff[t] = sh[t] - v;
}

__global__ void k_scan3(const int* __restrict__ tmp, const int* __restrict__ boff,
                        int* __restrict__ rowstart, int* __restrict__ cursor) {
    int t = threadIdx.x;
    int base = blockIdx.x * 1024 + t * 4;
    int off = boff[blockIdx.x];
    #pragma unroll
    for (int j = 0; j < 4; ++j) {
        int i = base + j;
        if (i < N_NODES) { int v = tmp[i] + off; rowstart[i] = v; cursor[i] = v; }
    }
    if (blockIdx.x == 0 && t == 0) rowstart[N_NODES] = N_EDGES;
}

__global__ void k_scatter(const int* __restrict__ src, const int* __restrict__ dst,
                          int* __restrict__ cursor, int* __restrict__ esrc) {
    int e = blockIdx.x * blockDim.x + threadIdx.x;
    if (e < N_EDGES) {
        int d = dst[e];
        int pos = atomicAdd(&cursor[d], 1);
        esrc[pos] = src[e];
    }
}

// exclusive scan of 512 graph counts; also init identity scale/shift for layer 0
__global__ void k_gscan(const int* __restrict__ gcnt, int* __restrict__ gstart,
                        float* __restrict__ ss0) {
    __shared__ int sh[512];
    int t = threadIdx.x;
    int v = gcnt[t];
    sh[t] = v;
    __syncthreads();
    for (int off = 1; off < 512; off <<= 1) {
        int x = (t >= off) ? sh[t - off] : 0;
        __syncthreads();
        sh[t] += x;
        __syncthreads();
    }
    gstart[t] = sh[t] - v;
    if (t == 511) gstart[512] = sh[511];
    if (t < 64) ss0[t] = 1.0f;
    else if (t < 128) ss0[t] = 0.0f;
}

// ---------------- GIN layer kernels ----------------

// One wave per dst node; lane = feature. Applies previous layer's BN
// (scale/shift) on the fly: sum over (v*s+b) = s*sum(v) + deg*b.
__global__ void k_agg(const float* __restrict__ hin, const float* __restrict__ ss,
                      const float* __restrict__ epsp, const int* __restrict__ rowstart,
                      const int* __restrict__ esrc, float* __restrict__ aggout) {
    int lane = threadIdx.x & 63;
    int wid = threadIdx.x >> 6;
    int node = blockIdx.x * 4 + wid;
    if (node >= N_NODES) return;
    float scale = ss[lane], shift = ss[64 + lane];
    float epsv = 1.0f + epsp[0];
    int s0 = rowstart[node], s1 = rowstart[node + 1];
    float sum = 0.0f;
    for (int i = s0; i < s1; i += 64) {
        int cnt = s1 - i; if (cnt > 64) cnt = 64;
        int src = (lane < cnt) ? esrc[i + lane] : 0;
        int j = 0;
        for (; j + 4 <= cnt; j += 4) {
            int a = __shfl(src, j), b = __shfl(src, j + 1);
            int c = __shfl(src, j + 2), d = __shfl(src, j + 3);
            float xa = hin[(size_t)a * 64 + lane];
            float xb = hin[(size_t)b * 64 + lane];
            float xc = hin[(size_t)c * 64 + lane];
            float xd = hin[(size_t)d * 64 + lane];
            sum += xa + xb + xc + xd;
        }
        for (; j < cnt; ++j) {
            int a = __shfl(src, j);
            sum += hin[(size_t)a * 64 + lane];
        }
    }
    float selfv = hin[(size_t)node * 64 + lane];
    float deg = (float)(s1 - s0);
    aggout[(size_t)node * 64 + lane] =
        scale * (sum + epsv * selfv) + (deg + epsv) * shift;
}

// C[N,64] = relu(A[N,64] @ W[64,64] + bias). 64 rows/block, 4x4 per thread.
// STATS: accumulate per-feature sum/sumsq into sums[128] (for BN).
// !STATS: block 0 zeroes sums[] (runs before the STATS gemm of the layer).
template <bool STATS>
__global__ void k_gemm(const float* __restrict__ A, const float* __restrict__ W,
                       const float* __restrict__ bias, float* __restrict__ C,
                       float* __restrict__ sums) {
    __shared__ float As[64 * 68];
    __shared__ float Ws[64 * 64];
    __shared__ float ssum[64];
    __shared__ float ssq[64];
    int tid = threadIdx.x;
    int r0 = blockIdx.x * 64;

    if (!STATS && blockIdx.x == 0 && tid < 128) sums[tid] = 0.0f;

    for (int i = tid; i < 4096; i += 256) Ws[i] = W[i];

    int col = tid & 63;
    int rg = tid >> 6;
    #pragma unroll
    for (int i = 0; i < 16; ++i) {
        int r = rg * 16 + i;
        int row = r0 + r;
        float v = (row < N_NODES) ? A[(size_t)row * 64 + col] : 0.0f;
        As[col * 68 + r] = v;
    }
    if (STATS && tid < 64) { ssum[tid] = 0.0f; ssq[tid] = 0.0f; }
    __syncthreads();

    int tx = tid & 15;
    int ty = tid >> 4;
    float acc[4][4] = {};
    #pragma unroll 8
    for (int k = 0; k < 64; ++k) {
        float4 av = *(const float4*)(&As[k * 68 + 4 * ty]);
        float4 bv = *(const float4*)(&Ws[k * 64 + 4 * tx]);
        acc[0][0] += av.x * bv.x; acc[0][1] += av.x * bv.y;
        acc[0][2] += av.x * bv.z; acc[0][3] += av.x * bv.w;
        acc[1][0] += av.y * bv.x; acc[1][1] += av.y * bv.y;
        acc[1][2] += av.y * bv.z; acc[1][3] += av.y * bv.w;
        acc[2][0] += av.z * bv.x; acc[2][1] += av.z * bv.y;
        acc[2][2] += av.z * bv.z; acc[2][3] += av.z * bv.w;
        acc[3][0] += av.w * bv.x; acc[3][1] += av.w * bv.y;
        acc[3][2] += av.w * bv.z; acc[3][3] += av.w * bv.w;
    }
    float b0 = bias[4 * tx + 0], b1 = bias[4 * tx + 1];
    float b2 = bias[4 * tx + 2], b3 = bias[4 * tx + 3];
    float ps[4] = {0, 0, 0, 0}, pq[4] = {0, 0, 0, 0};
    #pragma unroll
    for (int i = 0; i < 4; ++i) {
        int row = r0 + 4 * ty + i;
        if (row < N_NODES) {
            float4 o;
            o.x = fmaxf(acc[i][0] + b0, 0.0f);
            o.y = fmaxf(acc[i][1] + b1, 0.0f);
            o.z = fmaxf(acc[i][2] + b2, 0.0f);
            o.w = fmaxf(acc[i][3] + b3, 0.0f);
            *(float4*)(&C[(size_t)row * 64 + 4 * tx]) = o;
            if (STATS) {
                ps[0] += o.x; pq[0] += o.x * o.x;
                ps[1] += o.y; pq[1] += o.y * o.y;
                ps[2] += o.z; pq[2] += o.z * o.z;
                ps[3] += o.w; pq[3] += o.w * o.w;
            }
        }
    }
    if (STATS) {
        #pragma unroll
        for (int j = 0; j < 4; ++j) {
            atomicAdd(&ssum[4 * tx + j], ps[j]);
            atomicAdd(&ssq[4 * tx + j], pq[j]);
        }
        __syncthreads();
        if (tid < 64) {
            atomicAdd(&sums[tid], ssum[tid]);
            atomicAdd(&sums[64 + tid], ssq[tid]);
        }
    }
}

__global__ void k_bn(const float* __restrict__ sums, const float* __restrict__ g,
                     const float* __restrict__ be, float* __restrict__ ss_out) {
    int f = threadIdx.x;
    if (f < 64) {
        float mu = sums[f] / (float)N_NODES;
        float var = sums[64 + f] / (float)N_NODES - mu * mu;
        if (var < 0.0f) var = 0.0f;
        float inv = rsqrtf(var + BN_EPS);
        float sc = g[f] * inv;
        ss_out[f] = sc;
        ss_out[64 + f] = be[f] - mu * sc;
    }
}

// ---------------- pooling + FC + log_softmax ----------------

__global__ void k_pool(const float* __restrict__ h, const float* __restrict__ ss,
                       const int* __restrict__ gstart, const float* __restrict__ wfc,
                       const float* __restrict__ bfc, float* __restrict__ out) {
    __shared__ float pool[4][128];
    __shared__ float lg[4][8];
    int lane = threadIdx.x & 63;
    int w = threadIdx.x >> 6;
    int g = blockIdx.x * 4 + w;
    float scale = ss[lane], shift = ss[64 + lane];
    int s0 = gstart[g], s1 = gstart[g + 1];
    float sum = 0.0f, mx = -3.4e38f;
    for (int n = s0; n < s1; ++n) {
        float v = fmaf(h[(size_t)n * 64 + lane], scale, shift);
        sum += v;
        mx = fmaxf(mx, v);
    }
    int cnt = s1 - s0;
    float mean = sum / fmaxf((float)cnt, 1.0f);
    if (cnt == 0) mx = 0.0f;
    pool[w][lane] = mean;
    pool[w][64 + lane] = mx;
    __syncthreads();
    if (lane < NCLASS) {
        float acc = bfc[lane];
        for (int j = 0; j < 128; ++j) acc = fmaf(pool[w][j], wfc[j * NCLASS + lane], acc);
        lg[w][lane] = acc;
    }
    __syncthreads();
    if (lane < NCLASS) {
        float m = -3.4e38f;
        for (int c = 0; c < NCLASS; ++c) m = fmaxf(m, lg[w][c]);
        float s = 0.0f;
        for (int c = 0; c < NCLASS; ++c) s += expf(lg[w][c] - m);
        out[g * NCLASS + lane] = lg[w][lane] - m - logf(s);
    }
}

// ---------------- launch ----------------

extern "C" void kernel_launch(void* const* d_in, const int* in_sizes, int n_in,
                              void* d_out, int out_size, void* d_ws, size_t ws_size,
                              hipStream_t stream) {
    const float* x = (const float*)d_in[0];
    const int* ei = (const int*)d_in[1];
    const int* batch = (const int*)d_in[2];
    const int* esrc_in = ei;            // row 0: src
    const int* edst_in = ei + N_EDGES;  // row 1: dst

    // per-layer params: wa, ba, wb, bb, eps, g, be
    const float* wa[4] = {(const float*)d_in[3], (const float*)d_in[7],
                          (const float*)d_in[11], (const float*)d_in[11]};
    const float* ba[4] = {(const float*)d_in[4], (const float*)d_in[8],
                          (const float*)d_in[12], (const float*)d_in[12]};
    const float* wb[4] = {(const float*)d_in[5], (const float*)d_in[9],
                          (const float*)d_in[13], (const float*)d_in[13]};
    const float* bb[4] = {(const float*)d_in[6], (const float*)d_in[10],
                          (const float*)d_in[14], (const float*)d_in[14]};
    const float* epsv[4] = {(const float*)d_in[15], (const float*)d_in[18],
                            (const float*)d_in[21], (const float*)d_in[24]};
    const float* gg[4] = {(const float*)d_in[16], (const float*)d_in[19],
                          (const float*)d_in[22], (const float*)d_in[25]};
    const float* be[4] = {(const float*)d_in[17], (const float*)d_in[20],
                          (const float*)d_in[23], (const float*)d_in[26]};
    const float* wfc = (const float*)d_in[27];
    const float* bfc = (const float*)d_in[28];
    float* out = (float*)d_out;

    char* ws = (char*)d_ws;
    // workspace layout (bytes)
    int* esrc = (int*)(ws + 0);                    // 12,800,000
    int* deg = (int*)(ws + 12800000);              // 400,000
    int* gcnt = (int*)(ws + 13200000);             // 2,048
    int* tmp = (int*)(ws + 13202048);              // 400,000
    int* bsums = (int*)(ws + 13602048);            // 512
    int* boff = (int*)(ws + 13602560);             // 512
    int* rowstart = (int*)(ws + 13603072);         // 400,128
    int* cursor = (int*)(ws + 14003200);           // 400,000
    int* gstart = (int*)(ws + 14403200);           // 2,176
    float* ssbuf = (float*)(ws + 14405376);        // 5 * 128 floats = 2,560
    float* sums = (float*)(ws + 14407936);         // 512
    float* bufA = (float*)(ws + 14408448);         // 25,600,000
    float* bufB = (float*)(ws + 40008448);         // 25,600,000
    // total: 65,608,448 bytes

    // zero deg + gcnt in one shot (adjacent)
    hipMemsetAsync(ws + 12800000, 0, 402048, stream);

    const int NB = (N_NODES + 1023) / 1024;  // 98
    k_hist_edges<<<(N_EDGES + 255) / 256, 256, 0, stream>>>(edst_in, deg);
    k_hist_batch<<<(N_NODES + 255) / 256, 256, 0, stream>>>(batch, gcnt);
    k_scan1<<<NB, 256, 0, stream>>>(deg, tmp, bsums);
    k_scan2<<<1, 128, 0, stream>>>(bsums, boff, NB);
    k_scan3<<<NB, 256, 0, stream>>>(tmp, boff, rowstart, cursor);
    k_scatter<<<(N_EDGES + 255) / 256, 256, 0, stream>>>(esrc_in, edst_in, cursor, esrc);
    k_gscan<<<1, 512, 0, stream>>>(gcnt, gstart, ssbuf);

    const int GEMM_GRID = (N_NODES + 63) / 64;  // 1563
    for (int L = 0; L < 4; ++L) {
        const float* hin = (L == 0) ? x : bufB;
        const float* ssin = ssbuf + L * 128;
        float* ssout = ssbuf + (L + 1) * 128;
        k_agg<<<(N_NODES + 3) / 4, 256, 0, stream>>>(hin, ssin, epsv[L], rowstart,
                                                     esrc, bufA);
        k_gemm<false><<<GEMM_GRID, 256, 0, stream>>>(bufA, wa[L], ba[L], bufA, sums);
        k_gemm<true><<<GEMM_GRID, 256, 0, stream>>>(bufA, wb[L], bb[L], bufB, sums);
        k_bn<<<1, 64, 0, stream>>>(sums, gg[L], be[L], ssout);
    }

    k_pool<<<NGRAPH / 4, 256, 0, stream>>>(bufB, ssbuf + 4 * 128, gstart, wfc, bfc, out);
}

// Round 2
// 1069.000 us; speedup vs baseline: 1.3660x; 1.3660x over previous
//
#include <hip/hip_runtime.h>

#define N_NODES 100000
#define N_EDGES 3200000
#define HDIM 64
#define NGRAPH 512
#define NCLASS 6
#define BN_EPS 1e-5f

#define BSHIFT 8
#define NBUCK 391          // ceil(100000 / 256)
#define CHUNK 8192         // edges per block in bucket passes

// ---------------- CSR build: two-level counting sort ----------------

// Pass A: coarse histogram of dst>>8 into global bcnt[NBUCK]
__global__ void k_bhist(const int* __restrict__ dst, int* __restrict__ bcnt) {
    __shared__ int hist[NBUCK];
    int tid = threadIdx.x;
    long e0 = (long)blockIdx.x * CHUNK;
    for (int i = tid; i < NBUCK; i += 256) hist[i] = 0;
    __syncthreads();
    for (int i = tid; i < CHUNK; i += 256) {
        long e = e0 + i;
        if (e < N_EDGES) atomicAdd(&hist[dst[e] >> BSHIFT], 1);
    }
    __syncthreads();
    for (int i = tid; i < NBUCK; i += 256) {
        int c = hist[i];
        if (c) atomicAdd(&bcnt[i], c);
    }
}

__global__ void k_hist_batch(const int* __restrict__ batch, int* __restrict__ gcnt) {
    int i = blockIdx.x * blockDim.x + threadIdx.x;
    if (i < N_NODES) atomicAdd(&gcnt[batch[i]], 1);
}

// Scan bucket counts -> bstart/bcursor; also zero sums, set rowstart[N]
__global__ void k_bscan(const int* __restrict__ bcnt, int* __restrict__ bstart,
                        int* __restrict__ bcursor, float* __restrict__ sums,
                        int* __restrict__ rowstart) {
    __shared__ int sh[512];
    int t = threadIdx.x;
    int v = (t < NBUCK) ? bcnt[t] : 0;
    sh[t] = v;
    __syncthreads();
    for (int off = 1; off < 512; off <<= 1) {
        int x = (t >= off) ? sh[t - off] : 0;
        __syncthreads();
        sh[t] += x;
        __syncthreads();
    }
    int incl = sh[t];
    if (t < NBUCK) { bstart[t] = incl - v; bcursor[t] = incl - v; }
    if (t == NBUCK - 1) bstart[NBUCK] = incl;
    if (t < 128) sums[t] = 0.0f;
    if (t == 0) rowstart[N_NODES] = N_EDGES;
}

// Pass B: scatter (src,dst) pairs into bucket-grouped order.
__global__ void k_bscatter(const int* __restrict__ src, const int* __restrict__ dst,
                           int* __restrict__ bcursor, int2* __restrict__ pairs) {
    __shared__ int hist[NBUCK];
    __shared__ int base[NBUCK];
    int tid = threadIdx.x;
    long e0 = (long)blockIdx.x * CHUNK;
    for (int i = tid; i < NBUCK; i += 256) hist[i] = 0;
    __syncthreads();
    for (int i = tid; i < CHUNK; i += 256) {
        long e = e0 + i;
        if (e < N_EDGES) atomicAdd(&hist[dst[e] >> BSHIFT], 1);
    }
    __syncthreads();
    for (int i = tid; i < NBUCK; i += 256) {
        int c = hist[i];
        base[i] = c ? atomicAdd(&bcursor[i], c) : 0;
        hist[i] = 0;
    }
    __syncthreads();
    for (int i = tid; i < CHUNK; i += 256) {
        long e = e0 + i;
        if (e < N_EDGES) {
            int d = dst[e];
            int b = d >> BSHIFT;
            int r = atomicAdd(&hist[b], 1);
            pairs[base[b] + r] = make_int2(src[e], d);
        }
    }
}

// Pass C: one block per bucket; fine counting sort by dst within bucket.
// Emits rowstart[] and esrc[].
__global__ void k_bsort(const int2* __restrict__ pairs, const int* __restrict__ bstart,
                        int* __restrict__ rowstart, int* __restrict__ esrc) {
    __shared__ int deg[256];
    __shared__ int cur[256];
    int b = blockIdx.x;
    int tid = threadIdx.x;
    int p0 = bstart[b], p1 = bstart[b + 1];
    deg[tid] = 0;
    __syncthreads();
    for (int i = p0 + tid; i < p1; i += 256)
        atomicAdd(&deg[pairs[i].y & 255], 1);
    __syncthreads();
    int v = deg[tid];
    cur[tid] = v;
    __syncthreads();
    for (int off = 1; off < 256; off <<= 1) {
        int x = (tid >= off) ? cur[tid - off] : 0;
        __syncthreads();
        cur[tid] += x;
        __syncthreads();
    }
    int excl = cur[tid] - v;
    int node = (b << BSHIFT) + tid;
    if (node < N_NODES) rowstart[node] = p0 + excl;
    __syncthreads();   // everyone done reading cur during scan
    cur[tid] = excl;
    __syncthreads();
    for (int i = p0 + tid; i < p1; i += 256) {
        int2 pr = pairs[i];
        int r = atomicAdd(&cur[pr.y & 255], 1);
        esrc[p0 + r] = pr.x;
    }
}

// exclusive scan of 512 graph counts; also init identity scale/shift for layer 0
__global__ void k_gscan(const int* __restrict__ gcnt, int* __restrict__ gstart,
                        float* __restrict__ ss0) {
    __shared__ int sh[512];
    int t = threadIdx.x;
    int v = gcnt[t];
    sh[t] = v;
    __syncthreads();
    for (int off = 1; off < 512; off <<= 1) {
        int x = (t >= off) ? sh[t - off] : 0;
        __syncthreads();
        sh[t] += x;
        __syncthreads();
    }
    gstart[t] = sh[t] - v;
    if (t == 511) gstart[512] = sh[511];
    if (t < 64) ss0[t] = 1.0f;
    else if (t < 128) ss0[t] = 0.0f;
}

// ---------------- GIN layer kernels ----------------

// One wave per dst node; lane = feature. Applies previous layer's BN
// (scale/shift) on the fly: sum over (v*s+b) = s*sum(v) + deg*b.
__global__ void k_agg(const float* __restrict__ hin, const float* __restrict__ ss,
                      const float* __restrict__ epsp, const int* __restrict__ rowstart,
                      const int* __restrict__ esrc, float* __restrict__ aggout) {
    int lane = threadIdx.x & 63;
    int wid = threadIdx.x >> 6;
    int node = blockIdx.x * 4 + wid;
    if (node >= N_NODES) return;
    float scale = ss[lane], shift = ss[64 + lane];
    float epsv = 1.0f + epsp[0];
    int s0 = rowstart[node], s1 = rowstart[node + 1];
    float sum = 0.0f;
    for (int i = s0; i < s1; i += 64) {
        int cnt = s1 - i; if (cnt > 64) cnt = 64;
        int src = (lane < cnt) ? esrc[i + lane] : 0;
        int j = 0;
        for (; j + 8 <= cnt; j += 8) {
            int a0 = __shfl(src, j + 0), a1 = __shfl(src, j + 1);
            int a2 = __shfl(src, j + 2), a3 = __shfl(src, j + 3);
            int a4 = __shfl(src, j + 4), a5 = __shfl(src, j + 5);
            int a6 = __shfl(src, j + 6), a7 = __shfl(src, j + 7);
            float x0 = hin[(size_t)a0 * 64 + lane];
            float x1 = hin[(size_t)a1 * 64 + lane];
            float x2 = hin[(size_t)a2 * 64 + lane];
            float x3 = hin[(size_t)a3 * 64 + lane];
            float x4 = hin[(size_t)a4 * 64 + lane];
            float x5 = hin[(size_t)a5 * 64 + lane];
            float x6 = hin[(size_t)a6 * 64 + lane];
            float x7 = hin[(size_t)a7 * 64 + lane];
            sum += ((x0 + x1) + (x2 + x3)) + ((x4 + x5) + (x6 + x7));
        }
        for (; j < cnt; ++j) {
            int a = __shfl(src, j);
            sum += hin[(size_t)a * 64 + lane];
        }
    }
    float selfv = hin[(size_t)node * 64 + lane];
    float deg = (float)(s1 - s0);
    aggout[(size_t)node * 64 + lane] =
        scale * (sum + epsv * selfv) + (deg + epsv) * shift;
}

// Fused MLP: C = relu(relu(A@W1+b1)@W2+b2), accumulating BN stats into sums[128].
// 64 rows per block, 4x4 per thread, both weight matrices in LDS.
__global__ void k_mlp(const float* __restrict__ A, const float* __restrict__ W1,
                      const float* __restrict__ b1, const float* __restrict__ W2,
                      const float* __restrict__ b2, float* __restrict__ C,
                      float* __restrict__ sums) {
    __shared__ float As[64 * 68];
    __shared__ float Ws1[4096];
    __shared__ float Ws2[4096];
    __shared__ float ssum[64];
    __shared__ float ssq[64];
    int tid = threadIdx.x;
    int r0 = blockIdx.x * 64;

    for (int i = tid; i < 4096; i += 256) { Ws1[i] = W1[i]; Ws2[i] = W2[i]; }

    int col = tid & 63;
    int rg = tid >> 6;
    #pragma unroll
    for (int i = 0; i < 16; ++i) {
        int r = rg * 16 + i;
        int row = r0 + r;
        As[col * 68 + r] = (row < N_NODES) ? A[(size_t)row * 64 + col] : 0.0f;
    }
    if (tid < 64) { ssum[tid] = 0.0f; ssq[tid] = 0.0f; }
    __syncthreads();

    int tx = tid & 15;
    int ty = tid >> 4;

    float acc[4][4] = {};
    #pragma unroll 8
    for (int k = 0; k < 64; ++k) {
        float4 av = *(const float4*)(&As[k * 68 + 4 * ty]);
        float4 bv = *(const float4*)(&Ws1[k * 64 + 4 * tx]);
        acc[0][0] += av.x * bv.x; acc[0][1] += av.x * bv.y;
        acc[0][2] += av.x * bv.z; acc[0][3] += av.x * bv.w;
        acc[1][0] += av.y * bv.x; acc[1][1] += av.y * bv.y;
        acc[1][2] += av.y * bv.z; acc[1][3] += av.y * bv.w;
        acc[2][0] += av.z * bv.x; acc[2][1] += av.z * bv.y;
        acc[2][2] += av.z * bv.z; acc[2][3] += av.z * bv.w;
        acc[3][0] += av.w * bv.x; acc[3][1] += av.w * bv.y;
        acc[3][2] += av.w * bv.z; acc[3][3] += av.w * bv.w;
    }
    __syncthreads();  // all reads of As complete

    // relu(acc + b1) -> As transposed: As[k*68 + row], k = GEMM1 output col
    float c0 = b1[4 * tx + 0], c1 = b1[4 * tx + 1];
    float c2 = b1[4 * tx + 2], c3 = b1[4 * tx + 3];
    #pragma unroll
    for (int i = 0; i < 4; ++i) {
        int row = 4 * ty + i;
        As[(4 * tx + 0) * 68 + row] = fmaxf(acc[i][0] + c0, 0.0f);
        As[(4 * tx + 1) * 68 + row] = fmaxf(acc[i][1] + c1, 0.0f);
        As[(4 * tx + 2) * 68 + row] = fmaxf(acc[i][2] + c2, 0.0f);
        As[(4 * tx + 3) * 68 + row] = fmaxf(acc[i][3] + c3, 0.0f);
    }
    __syncthreads();

    float acc2[4][4] = {};
    #pragma unroll 8
    for (int k = 0; k < 64; ++k) {
        float4 av = *(const float4*)(&As[k * 68 + 4 * ty]);
        float4 bv = *(const float4*)(&Ws2[k * 64 + 4 * tx]);
        acc2[0][0] += av.x * bv.x; acc2[0][1] += av.x * bv.y;
        acc2[0][2] += av.x * bv.z; acc2[0][3] += av.x * bv.w;
        acc2[1][0] += av.y * bv.x; acc2[1][1] += av.y * bv.y;
        acc2[1][2] += av.y * bv.z; acc2[1][3] += av.y * bv.w;
        acc2[2][0] += av.z * bv.x; acc2[2][1] += av.z * bv.y;
        acc2[2][2] += av.z * bv.z; acc2[2][3] += av.z * bv.w;
        acc2[3][0] += av.w * bv.x; acc2[3][1] += av.w * bv.y;
        acc2[3][2] += av.w * bv.z; acc2[3][3] += av.w * bv.w;
    }

    float d0 = b2[4 * tx + 0], d1 = b2[4 * tx + 1];
    float d2 = b2[4 * tx + 2], d3 = b2[4 * tx + 3];
    float ps[4] = {0, 0, 0, 0}, pq[4] = {0, 0, 0, 0};
    #pragma unroll
    for (int i = 0; i < 4; ++i) {
        int row = r0 + 4 * ty + i;
        if (row < N_NODES) {
            float4 o;
            o.x = fmaxf(acc2[i][0] + d0, 0.0f);
            o.y = fmaxf(acc2[i][1] + d1, 0.0f);
            o.z = fmaxf(acc2[i][2] + d2, 0.0f);
            o.w = fmaxf(acc2[i][3] + d3, 0.0f);
            *(float4*)(&C[(size_t)row * 64 + 4 * tx]) = o;
            ps[0] += o.x; pq[0] += o.x * o.x;
            ps[1] += o.y; pq[1] += o.y * o.y;
            ps[2] += o.z; pq[2] += o.z * o.z;
            ps[3] += o.w; pq[3] += o.w * o.w;
        }
    }
    #pragma unroll
    for (int j = 0; j < 4; ++j) {
        atomicAdd(&ssum[4 * tx + j], ps[j]);
        atomicAdd(&ssq[4 * tx + j], pq[j]);
    }
    __syncthreads();
    if (tid < 64) {
        atomicAdd(&sums[tid], ssum[tid]);
        atomicAdd(&sums[64 + tid], ssq[tid]);
    }
}

// BN fold: emit scale/shift for the NEXT stage; zero sums for the next layer.
__global__ void k_bn(float* __restrict__ sums, const float* __restrict__ g,
                     const float* __restrict__ be, float* __restrict__ ss_out) {
    int f = threadIdx.x;
    if (f < 64) {
        float mu = sums[f] / (float)N_NODES;
        float var = sums[64 + f] / (float)N_NODES - mu * mu;
        if (var < 0.0f) var = 0.0f;
        float inv = rsqrtf(var + BN_EPS);
        float sc = g[f] * inv;
        ss_out[f] = sc;
        ss_out[64 + f] = be[f] - mu * sc;
        sums[f] = 0.0f;
        sums[64 + f] = 0.0f;
    }
}

// ---------------- pooling + FC + log_softmax ----------------

__global__ void k_pool(const float* __restrict__ h, const float* __restrict__ ss,
                       const int* __restrict__ gstart, const float* __restrict__ wfc,
                       const float* __restrict__ bfc, float* __restrict__ out) {
    __shared__ float pool[4][128];
    __shared__ float lg[4][8];
    int lane = threadIdx.x & 63;
    int w = threadIdx.x >> 6;
    int g = blockIdx.x * 4 + w;
    float scale = ss[lane], shift = ss[64 + lane];
    int s0 = gstart[g], s1 = gstart[g + 1];
    float sum = 0.0f, mx = -3.4e38f;
    for (int n = s0; n < s1; ++n) {
        float v = fmaf(h[(size_t)n * 64 + lane], scale, shift);
        sum += v;
        mx = fmaxf(mx, v);
    }
    int cnt = s1 - s0;
    float mean = sum / fmaxf((float)cnt, 1.0f);
    if (cnt == 0) mx = 0.0f;
    pool[w][lane] = mean;
    pool[w][64 + lane] = mx;
    __syncthreads();
    if (lane < NCLASS) {
        float acc = bfc[lane];
        for (int j = 0; j < 128; ++j) acc = fmaf(pool[w][j], wfc[j * NCLASS + lane], acc);
        lg[w][lane] = acc;
    }
    __syncthreads();
    if (lane < NCLASS) {
        float m = -3.4e38f;
        for (int c = 0; c < NCLASS; ++c) m = fmaxf(m, lg[w][c]);
        float s = 0.0f;
        for (int c = 0; c < NCLASS; ++c) s += expf(lg[w][c] - m);
        out[g * NCLASS + lane] = lg[w][lane] - m - logf(s);
    }
}

// ---------------- launch ----------------

extern "C" void kernel_launch(void* const* d_in, const int* in_sizes, int n_in,
                              void* d_out, int out_size, void* d_ws, size_t ws_size,
                              hipStream_t stream) {
    const float* x = (const float*)d_in[0];
    const int* ei = (const int*)d_in[1];
    const int* batch = (const int*)d_in[2];
    const int* esrc_in = ei;            // row 0: src
    const int* edst_in = ei + N_EDGES;  // row 1: dst

    const float* wa[4] = {(const float*)d_in[3], (const float*)d_in[7],
                          (const float*)d_in[11], (const float*)d_in[11]};
    const float* ba[4] = {(const float*)d_in[4], (const float*)d_in[8],
                          (const float*)d_in[12], (const float*)d_in[12]};
    const float* wb[4] = {(const float*)d_in[5], (const float*)d_in[9],
                          (const float*)d_in[13], (const float*)d_in[13]};
    const float* bb[4] = {(const float*)d_in[6], (const float*)d_in[10],
                          (const float*)d_in[14], (const float*)d_in[14]};
    const float* epsv[4] = {(const float*)d_in[15], (const float*)d_in[18],
                            (const float*)d_in[21], (const float*)d_in[24]};
    const float* gg[4] = {(const float*)d_in[16], (const float*)d_in[19],
                          (const float*)d_in[22], (const float*)d_in[25]};
    const float* be[4] = {(const float*)d_in[17], (const float*)d_in[20],
                          (const float*)d_in[23], (const float*)d_in[26]};
    const float* wfc = (const float*)d_in[27];
    const float* bfc = (const float*)d_in[28];
    float* out = (float*)d_out;

    char* ws = (char*)d_ws;
    // workspace layout (bytes); pairs region is reused as bufA after CSR build
    int2* pairs = (int2*)(ws + 0);             // 25,600,000
    float* bufA = (float*)(ws + 0);            // alias of pairs
    int* esrc = (int*)(ws + 25600000);         // 12,800,000
    int* rowstart = (int*)(ws + 38400000);     // 400,128
    int* bcnt = (int*)(ws + 38800128);         // 2,048
    int* bstart = (int*)(ws + 38802176);       // 2,048
    int* bcursor = (int*)(ws + 38804224);      // 2,048
    int* gcnt = (int*)(ws + 38806272);         // 2,048
    int* gstart = (int*)(ws + 38808320);       // 2,176
    float* ssbuf = (float*)(ws + 38810496);    // 2,560
    float* sums = (float*)(ws + 38813056);     // 512
    float* bufB = (float*)(ws + 38813568);     // 25,600,000
    // total: 64,413,568 bytes

    // zero bcnt..gcnt range in one shot (bstart/bcursor overwritten anyway)
    hipMemsetAsync(ws + 38800128, 0, 8192, stream);

    const int EB = (N_EDGES + CHUNK - 1) / CHUNK;  // 391
    k_bhist<<<EB, 256, 0, stream>>>(edst_in, bcnt);
    k_hist_batch<<<(N_NODES + 255) / 256, 256, 0, stream>>>(batch, gcnt);
    k_bscan<<<1, 512, 0, stream>>>(bcnt, bstart, bcursor, sums, rowstart);
    k_bscatter<<<EB, 256, 0, stream>>>(esrc_in, edst_in, bcursor, pairs);
    k_bsort<<<NBUCK, 256, 0, stream>>>(pairs, bstart, rowstart, esrc);
    k_gscan<<<1, 512, 0, stream>>>(gcnt, gstart, ssbuf);

    const int GEMM_GRID = (N_NODES + 63) / 64;  // 1563
    for (int L = 0; L < 4; ++L) {
        const float* hin = (L == 0) ? x : bufB;
        const float* ssin = ssbuf + L * 128;
        float* ssout = ssbuf + (L + 1) * 128;
        k_agg<<<(N_NODES + 3) / 4, 256, 0, stream>>>(hin, ssin, epsv[L], rowstart,
                                                     esrc, bufA);
        k_mlp<<<GEMM_GRID, 256, 0, stream>>>(bufA, wa[L], ba[L], wb[L], bb[L],
                                             bufB, sums);
        k_bn<<<1, 64, 0, stream>>>(sums, gg[L], be[L], ssout);
    }

    k_pool<<<NGRAPH / 4, 256, 0, stream>>>(bufB, ssbuf + 4 * 128, gstart, wfc, bfc, out);
}

// Round 5
// 832.492 us; speedup vs baseline: 1.7540x; 1.2841x over previous
//
#include <hip/hip_runtime.h>

#define N_NODES 100000
#define N_EDGES 3200000
#define NGRAPH 512
#define NCLASS 6
#define BN_EPS 1e-5f

#define BSHIFT 8
#define NBUCK 391          // ceil(100000 / 256)
#define CHUNK 8192         // edges per block in bucket passes
#define EB 391             // ceil(N_EDGES / CHUNK)

typedef unsigned short u16;
typedef unsigned int u32;
typedef __attribute__((ext_vector_type(8))) short bf16x8;
typedef __attribute__((ext_vector_type(4))) float f32x4;

__device__ __forceinline__ float bflo(u32 b) {
    u32 t = b << 16; return __builtin_bit_cast(float, t);
}
__device__ __forceinline__ float bfhi(u32 b) {
    u32 t = b & 0xffff0000u; return __builtin_bit_cast(float, t);
}
__device__ __forceinline__ u16 f2bf(float f) {   // round-to-nearest-even
    u32 u = __builtin_bit_cast(u32, f);
    return (u16)((u + 0x7fffu + ((u >> 16) & 1u)) >> 16);
}

// ---------------- input cast: x fp32 -> bf16 ----------------
__global__ void k_cast(const float* __restrict__ x, u16* __restrict__ xb) {
    int base = (blockIdx.x * 256 + threadIdx.x) * 4;
    if (base < N_NODES * 64) {
        float4 v = *(const float4*)(x + base);
        ushort4 o = make_ushort4(f2bf(v.x), f2bf(v.y), f2bf(v.z), f2bf(v.w));
        *(ushort4*)(xb + base) = o;
    }
}

// ---------------- CSR build ----------------

// blocks [0,EB): coarse hist of dst>>8; blocks [EB, EB+391): batch hist
__global__ void k_hist(const int* __restrict__ dst, const int* __restrict__ batch,
                       int* __restrict__ bcnt, int* __restrict__ gcnt) {
    __shared__ int hist[NBUCK];
    int tid = threadIdx.x;
    int b = blockIdx.x;
    if (b < EB) {
        long e0 = (long)b * CHUNK;
        for (int i = tid; i < NBUCK; i += 256) hist[i] = 0;
        __syncthreads();
        for (int i = tid; i < CHUNK; i += 256) {
            long e = e0 + i;
            if (e < N_EDGES) atomicAdd(&hist[dst[e] >> BSHIFT], 1);
        }
        __syncthreads();
        for (int i = tid; i < NBUCK; i += 256) {
            int c = hist[i];
            if (c) atomicAdd(&bcnt[i], c);
        }
    } else {
        int i = (b - EB) * 256 + tid;
        if (i < N_NODES) atomicAdd(&gcnt[batch[i]], 1);
    }
}

// block 0: bucket scan; block 1: graph scan
__global__ void k_scan(const int* __restrict__ bcnt, int* __restrict__ bstart,
                       int* __restrict__ bcursor, const int* __restrict__ gcnt,
                       int* __restrict__ gstart, int* __restrict__ rowstart) {
    __shared__ int sh[512];
    int t = threadIdx.x;
    if (blockIdx.x == 0) {
        int v = (t < NBUCK) ? bcnt[t] : 0;
        sh[t] = v;
        __syncthreads();
        for (int off = 1; off < 512; off <<= 1) {
            int x = (t >= off) ? sh[t - off] : 0;
            __syncthreads();
            sh[t] += x;
            __syncthreads();
        }
        int incl = sh[t];
        if (t < NBUCK) { bstart[t] = incl - v; bcursor[t] = incl - v; }
        if (t == NBUCK - 1) bstart[NBUCK] = incl;
        if (t == 0) rowstart[N_NODES] = N_EDGES;
    } else {
        int v = gcnt[t];
        sh[t] = v;
        __syncthreads();
        for (int off = 1; off < 512; off <<= 1) {
            int x = (t >= off) ? sh[t - off] : 0;
            __syncthreads();
            sh[t] += x;
            __syncthreads();
        }
        gstart[t] = sh[t] - v;
        if (t == 511) gstart[512] = sh[511];
    }
}

// scatter packed (src<<8 | dst&255) into bucket-grouped order
__global__ void k_bscatter(const int* __restrict__ src, const int* __restrict__ dst,
                           int* __restrict__ bcursor, int* __restrict__ pairs) {
    __shared__ int hist[NBUCK];
    __shared__ int base[NBUCK];
    int tid = threadIdx.x;
    long e0 = (long)blockIdx.x * CHUNK;
    for (int i = tid; i < NBUCK; i += 256) hist[i] = 0;
    __syncthreads();
    for (int i = tid; i < CHUNK; i += 256) {
        long e = e0 + i;
        if (e < N_EDGES) atomicAdd(&hist[dst[e] >> BSHIFT], 1);
    }
    __syncthreads();
    for (int i = tid; i < NBUCK; i += 256) {
        int c = hist[i];
        base[i] = c ? atomicAdd(&bcursor[i], c) : 0;
        hist[i] = 0;
    }
    __syncthreads();
    for (int i = tid; i < CHUNK; i += 256) {
        long e = e0 + i;
        if (e < N_EDGES) {
            int d = dst[e];
            int b = d >> BSHIFT;
            int r = atomicAdd(&hist[b], 1);
            pairs[base[b] + r] = (src[e] << 8) | (d & 255);
        }
    }
}

// per-bucket fine counting sort -> rowstart, esrc
__global__ void k_bsort(const int* __restrict__ pairs, const int* __restrict__ bstart,
                        int* __restrict__ rowstart, int* __restrict__ esrc) {
    __shared__ int deg[256];
    __shared__ int cur[256];
    int b = blockIdx.x;
    int tid = threadIdx.x;
    int p0 = bstart[b], p1 = bstart[b + 1];
    deg[tid] = 0;
    __syncthreads();
    for (int i = p0 + tid; i < p1; i += 256)
        atomicAdd(&deg[pairs[i] & 255], 1);
    __syncthreads();
    int v = deg[tid];
    cur[tid] = v;
    __syncthreads();
    for (int off = 1; off < 256; off <<= 1) {
        int x = (tid >= off) ? cur[tid - off] : 0;
        __syncthreads();
        cur[tid] += x;
        __syncthreads();
    }
    int excl = cur[tid] - v;
    int node = (b << BSHIFT) + tid;
    if (node < N_NODES) rowstart[node] = p0 + excl;
    __syncthreads();
    cur[tid] = excl;
    __syncthreads();
    for (int i = p0 + tid; i < p1; i += 256) {
        u32 pr = (u32)pairs[i];
        int r = atomicAdd(&cur[pr & 255], 1);
        esrc[p0 + r] = (int)(pr >> 8);
    }
}

// ---------------- aggregation (bf16 in/out, BN folded on the fly) ----------------
// One wave per dst node; lane halves split edges; each lane owns 2 features.
// NOTE: every __shfl below executes with ALL 64 lanes active and a source
// lane that is < cnt (bpermute from an exec-masked lane is undefined — the
// R3/R4 correctness bug).
__global__ void k_agg(const u16* __restrict__ hin, const float* __restrict__ sums,
                      const float* __restrict__ g, const float* __restrict__ be,
                      const float* __restrict__ epsp, const int* __restrict__ rowstart,
                      const int* __restrict__ esrc, u16* __restrict__ out) {
    int lane = threadIdx.x & 63;
    int wid = threadIdx.x >> 6;
    int node = blockIdx.x * 4 + wid;
    if (node >= N_NODES) return;
    int half = lane >> 5;
    int li = lane & 31;
    int f0 = 2 * li;
    float sc0 = 1.f, sh0 = 0.f, sc1 = 1.f, sh1 = 0.f;
    if (sums != nullptr) {
        float inv = 1.0f / (float)N_NODES;
        float mu0 = sums[f0] * inv, mu1 = sums[f0 + 1] * inv;
        float v0 = fmaxf(sums[64 + f0] * inv - mu0 * mu0, 0.f);
        float v1 = fmaxf(sums[64 + f0 + 1] * inv - mu1 * mu1, 0.f);
        sc0 = g[f0] * rsqrtf(v0 + BN_EPS); sh0 = be[f0] - mu0 * sc0;
        sc1 = g[f0 + 1] * rsqrtf(v1 + BN_EPS); sh1 = be[f0 + 1] - mu1 * sc1;
    }
    float epsv = 1.0f + epsp[0];
    int e0 = rowstart[node], e1 = rowstart[node + 1];
    float s0 = 0.f, s1 = 0.f;
    for (int i = e0; i < e1; i += 64) {
        int cnt = min(e1 - i, 64);
        int src = (lane < cnt) ? esrc[i + lane] : 0;
        int j = 0;
        for (; j + 8 <= cnt; j += 8) {   // sources j..j+7 all < cnt, all lanes active
            int a0 = __shfl(src, j + 0 + half);
            int a1 = __shfl(src, j + 2 + half);
            int a2 = __shfl(src, j + 4 + half);
            int a3 = __shfl(src, j + 6 + half);
            u32 b0 = *(const u32*)(hin + (size_t)a0 * 64 + f0);
            u32 b1 = *(const u32*)(hin + (size_t)a1 * 64 + f0);
            u32 b2 = *(const u32*)(hin + (size_t)a2 * 64 + f0);
            u32 b3 = *(const u32*)(hin + (size_t)a3 * 64 + f0);
            s0 += (bflo(b0) + bflo(b1)) + (bflo(b2) + bflo(b3));
            s1 += (bfhi(b0) + bfhi(b1)) + (bfhi(b2) + bfhi(b3));
        }
        for (; j < cnt; j += 2) {        // uniform loop bound; shfl kept unguarded
            int jj = j + half;
            int a = __shfl(src, (jj < cnt) ? jj : (cnt - 1));  // clamp: valid+active src
            u32 b = *(const u32*)(hin + (size_t)a * 64 + f0);
            if (jj < cnt) { s0 += bflo(b); s1 += bfhi(b); }    // gate accumulate only
        }
    }
    s0 += __shfl_xor(s0, 32);
    s1 += __shfl_xor(s1, 32);
    u32 sb = *(const u32*)(hin + (size_t)node * 64 + f0);
    float deg = (float)(e1 - e0);
    float o0 = sc0 * (s0 + epsv * bflo(sb)) + (deg + epsv) * sh0;
    float o1 = sc1 * (s1 + epsv * bfhi(sb)) + (deg + epsv) * sh1;
    if (half == 0) {
        u32 pk = (u32)f2bf(o0) | ((u32)f2bf(o1) << 16);
        *(u32*)(out + (size_t)node * 64 + f0) = pk;
    }
}

// ---------------- fused MLP via bf16 MFMA ----------------
// 64 rows/block, 4 waves; wave w owns rows [16w,16w+16). A-frags straight from
// global (16B/lane coalesced). Weights transposed bf16 in LDS (stride 72).
// GEMM1->GEMM2 handoff via wave-private LDS rows (in-order DS per wave).
// MFMA layouts (m89/m74-verified): A[m=lane&15][k=(lane>>4)*8+j];
// B[k][n=lane&15]; D col=lane&15, row=(lane>>4)*4+r.
__global__ __launch_bounds__(256) void k_mlp(
    const u16* __restrict__ A, const float* __restrict__ W1,
    const float* __restrict__ b1, const float* __restrict__ W2,
    const float* __restrict__ b2, u16* __restrict__ C, float* __restrict__ sums) {
    __shared__ u16 Wt1[64 * 72];
    __shared__ u16 Wt2[64 * 72];
    __shared__ u16 Hs[64 * 72];
    __shared__ float ssum[64];
    __shared__ float ssq[64];
    int tid = threadIdx.x;
    int r0 = blockIdx.x * 64;
    {   // stage W transposed: Wt[c*72 + k] = W[k*64 + c]
        int k = tid & 63;
        int cbase = tid >> 6;
        for (int c = cbase; c < 64; c += 4) {
            Wt1[c * 72 + k] = f2bf(W1[k * 64 + c]);
            Wt2[c * 72 + k] = f2bf(W2[k * 64 + c]);
        }
    }
    if (tid < 64) { ssum[tid] = 0.f; ssq[tid] = 0.f; }
    __syncthreads();

    int lane = tid & 63;
    int w = tid >> 6;
    int m = lane & 15;   // A/D row index within 16-tile; B col index
    int q = lane >> 4;   // quad: k-chunk for A/B, row group for D
    int rowg = r0 + w * 16 + m;
    int rowc = min(rowg, N_NODES - 1);

    // GEMM1: D = A @ W1  (A rows = agg output rows)
    bf16x8 a0 = *(const bf16x8*)(A + (size_t)rowc * 64 + q * 8);
    bf16x8 a1 = *(const bf16x8*)(A + (size_t)rowc * 64 + 32 + q * 8);
    f32x4 acc[4];
    #pragma unroll
    for (int c = 0; c < 4; ++c) {
        acc[c] = (f32x4){0.f, 0.f, 0.f, 0.f};
        bf16x8 bA = *(const bf16x8*)(&Wt1[(c * 16 + m) * 72 + q * 8]);
        bf16x8 bB = *(const bf16x8*)(&Wt1[(c * 16 + m) * 72 + 32 + q * 8]);
        acc[c] = __builtin_amdgcn_mfma_f32_16x16x32_bf16(a0, bA, acc[c], 0, 0, 0);
        acc[c] = __builtin_amdgcn_mfma_f32_16x16x32_bf16(a1, bB, acc[c], 0, 0, 0);
    }
    // epilogue1: relu -> Hs (wave-private rows, bf16). D[row=q*4+r][col=c*16+m]
    #pragma unroll
    for (int c = 0; c < 4; ++c) {
        int col = c * 16 + m;
        float bb = b1[col];
        #pragma unroll
        for (int r = 0; r < 4; ++r) {
            int rl = w * 16 + q * 4 + r;
            Hs[rl * 72 + col] = f2bf(fmaxf(acc[c][r] + bb, 0.f));
        }
    }
    // GEMM2: A from Hs (same wave's rows; DS ops in-order per wave)
    bf16x8 h0 = *(const bf16x8*)(&Hs[(w * 16 + m) * 72 + q * 8]);
    bf16x8 h1 = *(const bf16x8*)(&Hs[(w * 16 + m) * 72 + 32 + q * 8]);
    f32x4 acc2[4];
    #pragma unroll
    for (int c = 0; c < 4; ++c) {
        acc2[c] = (f32x4){0.f, 0.f, 0.f, 0.f};
        bf16x8 bA = *(const bf16x8*)(&Wt2[(c * 16 + m) * 72 + q * 8]);
        bf16x8 bB = *(const bf16x8*)(&Wt2[(c * 16 + m) * 72 + 32 + q * 8]);
        acc2[c] = __builtin_amdgcn_mfma_f32_16x16x32_bf16(h0, bA, acc2[c], 0, 0, 0);
        acc2[c] = __builtin_amdgcn_mfma_f32_16x16x32_bf16(h1, bB, acc2[c], 0, 0, 0);
    }
    // epilogue2: relu, store bf16, BN stats
    #pragma unroll
    for (int c = 0; c < 4; ++c) {
        int col = c * 16 + m;
        float bb = b2[col];
        float psum = 0.f, psq = 0.f;
        #pragma unroll
        for (int r = 0; r < 4; ++r) {
            int rg = r0 + w * 16 + q * 4 + r;
            if (rg < N_NODES) {
                float o = fmaxf(acc2[c][r] + bb, 0.f);
                C[(size_t)rg * 64 + col] = f2bf(o);
                psum += o;
                psq += o * o;
            }
        }
        atomicAdd(&ssum[col], psum);
        atomicAdd(&ssq[col], psq);
    }
    __syncthreads();
    if (tid < 64) {
        atomicAdd(&sums[tid], ssum[tid]);
        atomicAdd(&sums[64 + tid], ssq[tid]);
    }
}

// ---------------- pooling + FC + log_softmax ----------------
__global__ void k_pool(const u16* __restrict__ h, const float* __restrict__ sums,
                       const float* __restrict__ g4, const float* __restrict__ be4,
                       const int* __restrict__ gstart, const float* __restrict__ wfc,
                       const float* __restrict__ bfc, float* __restrict__ out) {
    __shared__ float smean[2][128];
    __shared__ float smax[2][128];
    __shared__ float lg[2][8];
    int tid = threadIdx.x;
    int lane = tid & 63;
    int w = tid >> 6;
    int gi = w >> 1;
    int part = w & 1;
    int gr = blockIdx.x * 2 + gi;
    int half = lane >> 5;
    int li = lane & 31;
    int f0 = 2 * li;
    float inv = 1.0f / (float)N_NODES;
    float mu0 = sums[f0] * inv, mu1 = sums[f0 + 1] * inv;
    float v0 = fmaxf(sums[64 + f0] * inv - mu0 * mu0, 0.f);
    float v1 = fmaxf(sums[64 + f0 + 1] * inv - mu1 * mu1, 0.f);
    float sc0 = g4[f0] * rsqrtf(v0 + BN_EPS), sh0 = be4[f0] - mu0 * sc0;
    float sc1 = g4[f0 + 1] * rsqrtf(v1 + BN_EPS), sh1 = be4[f0 + 1] - mu1 * sc1;
    int s0n = gstart[gr], s1n = gstart[gr + 1];
    int cnt = s1n - s0n;
    int mid = s0n + (cnt >> 1);
    int a = part ? mid : s0n;
    int b = part ? s1n : mid;
    float sum0 = 0.f, sum1 = 0.f, mx0 = -3.4e38f, mx1 = -3.4e38f;
    for (int n = a + half; n < b; n += 2) {
        u32 bits = *(const u32*)(h + (size_t)n * 64 + f0);
        float x0 = fmaf(bflo(bits), sc0, sh0);
        float x1 = fmaf(bfhi(bits), sc1, sh1);
        sum0 += x0; sum1 += x1;
        mx0 = fmaxf(mx0, x0); mx1 = fmaxf(mx1, x1);
    }
    sum0 += __shfl_xor(sum0, 32);
    sum1 += __shfl_xor(sum1, 32);
    mx0 = fmaxf(mx0, __shfl_xor(mx0, 32));
    mx1 = fmaxf(mx1, __shfl_xor(mx1, 32));
    if (half == 0 && part == 0) {
        smean[gi][f0] = sum0; smean[gi][f0 + 1] = sum1;
        smax[gi][f0] = mx0;   smax[gi][f0 + 1] = mx1;
    }
    __syncthreads();
    if (half == 0 && part == 1) {
        float m0 = fmaxf(smax[gi][f0], mx0), m1 = fmaxf(smax[gi][f0 + 1], mx1);
        float t0 = smean[gi][f0] + sum0, t1 = smean[gi][f0 + 1] + sum1;
        float fc = fmaxf((float)cnt, 1.f);
        smean[gi][f0] = t0 / fc;
        smean[gi][f0 + 1] = t1 / fc;
        smax[gi][f0] = (cnt > 0) ? m0 : 0.f;
        smax[gi][f0 + 1] = (cnt > 0) ? m1 : 0.f;
    }
    __syncthreads();
    if (part == 0 && lane < NCLASS) {
        float acc = bfc[lane];
        for (int j = 0; j < 64; ++j) acc = fmaf(smean[gi][j], wfc[j * NCLASS + lane], acc);
        for (int j = 0; j < 64; ++j) acc = fmaf(smax[gi][j], wfc[(64 + j) * NCLASS + lane], acc);
        lg[gi][lane] = acc;
    }
    __syncthreads();
    if (part == 0 && lane < NCLASS) {
        float mm = -3.4e38f;
        for (int c = 0; c < NCLASS; ++c) mm = fmaxf(mm, lg[gi][c]);
        float se = 0.f;
        for (int c = 0; c < NCLASS; ++c) se += expf(lg[gi][c] - mm);
        out[gr * NCLASS + lane] = lg[gi][lane] - mm - logf(se);
    }
}

// ---------------- launch ----------------

extern "C" void kernel_launch(void* const* d_in, const int* in_sizes, int n_in,
                              void* d_out, int out_size, void* d_ws, size_t ws_size,
                              hipStream_t stream) {
    const float* x = (const float*)d_in[0];
    const int* ei = (const int*)d_in[1];
    const int* batch = (const int*)d_in[2];
    const int* esrc_in = ei;
    const int* edst_in = ei + N_EDGES;

    const float* wa[4] = {(const float*)d_in[3], (const float*)d_in[7],
                          (const float*)d_in[11], (const float*)d_in[11]};
    const float* ba[4] = {(const float*)d_in[4], (const float*)d_in[8],
                          (const float*)d_in[12], (const float*)d_in[12]};
    const float* wb[4] = {(const float*)d_in[5], (const float*)d_in[9],
                          (const float*)d_in[13], (const float*)d_in[13]};
    const float* bb[4] = {(const float*)d_in[6], (const float*)d_in[10],
                          (const float*)d_in[14], (const float*)d_in[14]};
    const float* epsv[4] = {(const float*)d_in[15], (const float*)d_in[18],
                            (const float*)d_in[21], (const float*)d_in[24]};
    const float* gg[4] = {(const float*)d_in[16], (const float*)d_in[19],
                          (const float*)d_in[22], (const float*)d_in[25]};
    const float* bee[4] = {(const float*)d_in[17], (const float*)d_in[20],
                           (const float*)d_in[23], (const float*)d_in[26]};
    const float* wfc = (const float*)d_in[27];
    const float* bfc = (const float*)d_in[28];
    float* out = (float*)d_out;

    char* ws = (char*)d_ws;
    int* pairs = (int*)(ws + 0);               // 12,800,000 (dead after k_bsort)
    u16* bufA = (u16*)(ws + 0);                // alias of pairs
    int* esrc = (int*)(ws + 12800000);         // 12,800,000
    u16* xb = (u16*)(ws + 25600000);           // 12,800,000
    u16* bufB = (u16*)(ws + 38400000);         // 12,800,000
    int* rowstart = (int*)(ws + 51200000);     // 400,128
    char* zbase = ws + 51600128;
    int* bcnt = (int*)(zbase);                 // 2,048
    int* gcnt = (int*)(zbase + 2048);          // 2,048
    float* sumsL = (float*)(zbase + 4096);     // 4 layers x 128 f32 = 2,048
    int* bstart = (int*)(zbase + 6144);        // 2,048
    int* bcursor = (int*)(zbase + 8192);       // 2,048
    int* gstart = (int*)(zbase + 10240);       // 2,176
    // total: 51,612,544 bytes

    hipMemsetAsync(zbase, 0, 6144, stream);    // bcnt + gcnt + sumsL

    k_cast<<<(N_NODES * 64 / 4 + 255) / 256, 256, 0, stream>>>(x, xb);
    k_hist<<<EB + 391, 256, 0, stream>>>(edst_in, batch, bcnt, gcnt);
    k_scan<<<2, 512, 0, stream>>>(bcnt, bstart, bcursor, gcnt, gstart, rowstart);
    k_bscatter<<<EB, 256, 0, stream>>>(esrc_in, edst_in, bcursor, pairs);
    k_bsort<<<NBUCK, 256, 0, stream>>>(pairs, bstart, rowstart, esrc);

    const int AGG_GRID = (N_NODES + 3) / 4;
    const int MLP_GRID = (N_NODES + 63) / 64;
    for (int L = 0; L < 4; ++L) {
        const u16* hin = (L == 0) ? xb : bufB;
        const float* sp = (L == 0) ? nullptr : (sumsL + (L - 1) * 128);
        const float* gp = (L == 0) ? gg[0] : gg[L - 1];
        const float* bp = (L == 0) ? bee[0] : bee[L - 1];
        k_agg<<<AGG_GRID, 256, 0, stream>>>(hin, sp, gp, bp, epsv[L], rowstart,
                                            esrc, bufA);
        k_mlp<<<MLP_GRID, 256, 0, stream>>>(bufA, wa[L], ba[L], wb[L], bb[L],
                                            bufB, sumsL + L * 128);
    }

    k_pool<<<NGRAPH / 2, 256, 0, stream>>>(bufB, sumsL + 3 * 128, gg[3], bee[3],
                                           gstart, wfc, bfc, out);
}

// Round 6
// 785.107 us; speedup vs baseline: 1.8599x; 1.0604x over previous
//
#include <hip/hip_runtime.h>

#define N_NODES 100000
#define N_EDGES 3200000
#define NGRAPH 512
#define NCLASS 6
#define BN_EPS 1e-5f

#define BSHIFT 8
#define NBUCK 391          // ceil(100000 / 256)
#define CHUNK 8192         // edges per block in bucket passes
#define EB 391             // ceil(N_EDGES / CHUNK)
#define NBLK_NODE 391      // ceil(N_NODES / 256)

typedef unsigned short u16;
typedef unsigned int u32;
typedef __attribute__((ext_vector_type(8))) short bf16x8;
typedef __attribute__((ext_vector_type(4))) float f32x4;

__device__ __forceinline__ float bflo(u32 b) {
    u32 t = b << 16; return __builtin_bit_cast(float, t);
}
__device__ __forceinline__ float bfhi(u32 b) {
    u32 t = b & 0xffff0000u; return __builtin_bit_cast(float, t);
}
__device__ __forceinline__ u16 f2bf(float f) {   // round-to-nearest-even
    u32 u = __builtin_bit_cast(u32, f);
    return (u16)((u + 0x7fffu + ((u >> 16) & 1u)) >> 16);
}

// ---------------- input cast: x fp32 -> bf16 ----------------
__global__ void k_cast(const float* __restrict__ x, u16* __restrict__ xb) {
    int base = (blockIdx.x * 256 + threadIdx.x) * 4;
    if (base < N_NODES * 64) {
        float4 v = *(const float4*)(x + base);
        ushort4 o = make_ushort4(f2bf(v.x), f2bf(v.y), f2bf(v.z), f2bf(v.w));
        *(ushort4*)(xb + base) = o;
    }
}

// ---------------- CSR build ----------------

// blocks [0,EB): per-block coarse hist of dst>>8 -> blockhist[b][k] (plain stores).
// blocks [EB, EB+NBLK_NODE): gstart via boundary detection on sorted batch
// (NO atomics — the R5 k_hist 81us stall was a 195-deep chain of same-address
//  cross-XCD global atomics from sorted batch).
__global__ void k_hist(const int* __restrict__ dst, const int* __restrict__ batch,
                       int* __restrict__ blockhist, int* __restrict__ gstart) {
    __shared__ int hist[NBUCK];
    int tid = threadIdx.x;
    int b = blockIdx.x;
    if (b < EB) {
        long e0 = (long)b * CHUNK;
        for (int i = tid; i < NBUCK; i += 256) hist[i] = 0;
        __syncthreads();
        for (int i = tid; i < CHUNK; i += 256) {
            long e = e0 + i;
            if (e < N_EDGES) atomicAdd(&hist[dst[e] >> BSHIFT], 1);
        }
        __syncthreads();
        for (int i = tid; i < NBUCK; i += 256) blockhist[b * NBUCK + i] = hist[i];
    } else {
        int i = (b - EB) * 256 + tid;
        if (i < N_NODES) {
            int bi = batch[i];
            int bp = (i == 0) ? -1 : batch[i - 1];
            for (int g = bp + 1; g <= bi; ++g) gstart[g] = i;
            if (i == N_NODES - 1)
                for (int g = bi + 1; g <= NGRAPH; ++g) gstart[g] = N_NODES;
        }
    }
}

// one block per bucket k: exclusive-scan blockhist column k over the 391
// edge-blocks (in place) and emit the column total.
__global__ void k_scan_cols(int* __restrict__ blockhist, int* __restrict__ colsum) {
    __shared__ int sh[512];
    int k = blockIdx.x;
    int t = threadIdx.x;
    int v = (t < EB) ? blockhist[t * NBUCK + k] : 0;
    sh[t] = v;
    __syncthreads();
    for (int off = 1; off < 512; off <<= 1) {
        int x = (t >= off) ? sh[t - off] : 0;
        __syncthreads();
        sh[t] += x;
        __syncthreads();
    }
    if (t < EB) blockhist[t * NBUCK + k] = sh[t] - v;
    if (t == 511) colsum[k] = sh[511];
}

// single block: scan bucket totals -> bstart; set rowstart[N]
__global__ void k_scan_b(const int* __restrict__ colsum, int* __restrict__ bstart,
                         int* __restrict__ rowstart) {
    __shared__ int sh[512];
    int t = threadIdx.x;
    int v = (t < NBUCK) ? colsum[t] : 0;
    sh[t] = v;
    __syncthreads();
    for (int off = 1; off < 512; off <<= 1) {
        int x = (t >= off) ? sh[t - off] : 0;
        __syncthreads();
        sh[t] += x;
        __syncthreads();
    }
    if (t < NBUCK) bstart[t] = sh[t] - v;
    if (t == NBUCK - 1) bstart[NBUCK] = sh[t];
    if (t == 0) rowstart[N_NODES] = N_EDGES;
}

// scatter packed (src<<8 | dst&255) into bucket-grouped order using the
// precomputed per-block bases (no re-histogram, no global cursor atomics).
__global__ void k_bscatter(const int* __restrict__ src, const int* __restrict__ dst,
                           const int* __restrict__ bstart,
                           const int* __restrict__ blockhist, int* __restrict__ pairs) {
    __shared__ int base[NBUCK];
    __shared__ int hist[NBUCK];
    int tid = threadIdx.x;
    int b = blockIdx.x;
    long e0 = (long)b * CHUNK;
    for (int k = tid; k < NBUCK; k += 256) {
        base[k] = bstart[k] + blockhist[b * NBUCK + k];
        hist[k] = 0;
    }
    __syncthreads();
    for (int i = tid; i < CHUNK; i += 256) {
        long e = e0 + i;
        if (e < N_EDGES) {
            int d = dst[e];
            int k = d >> BSHIFT;
            int r = atomicAdd(&hist[k], 1);
            pairs[base[k] + r] = (src[e] << 8) | (d & 255);
        }
    }
}

// per-bucket fine counting sort -> rowstart, esrc
__global__ void k_bsort(const int* __restrict__ pairs, const int* __restrict__ bstart,
                        int* __restrict__ rowstart, int* __restrict__ esrc) {
    __shared__ int deg[256];
    __shared__ int cur[256];
    int b = blockIdx.x;
    int tid = threadIdx.x;
    int p0 = bstart[b], p1 = bstart[b + 1];
    deg[tid] = 0;
    __syncthreads();
    for (int i = p0 + tid; i < p1; i += 256)
        atomicAdd(&deg[pairs[i] & 255], 1);
    __syncthreads();
    int v = deg[tid];
    cur[tid] = v;
    __syncthreads();
    for (int off = 1; off < 256; off <<= 1) {
        int x = (tid >= off) ? cur[tid - off] : 0;
        __syncthreads();
        cur[tid] += x;
        __syncthreads();
    }
    int excl = cur[tid] - v;
    int node = (b << BSHIFT) + tid;
    if (node < N_NODES) rowstart[node] = p0 + excl;
    __syncthreads();
    cur[tid] = excl;
    __syncthreads();
    for (int i = p0 + tid; i < p1; i += 256) {
        u32 pr = (u32)pairs[i];
        int r = atomicAdd(&cur[pr & 255], 1);
        esrc[p0 + r] = (int)(pr >> 8);
    }
}

// ---------------- aggregation (bf16 in/out, BN folded on the fly) ----------------
// One wave per dst node; lane halves split edges; each lane owns 2 features.
// Every __shfl executes with ALL 64 lanes active and a source lane < cnt.
__global__ void k_agg(const u16* __restrict__ hin, const float* __restrict__ sums,
                      const float* __restrict__ g, const float* __restrict__ be,
                      const float* __restrict__ epsp, const int* __restrict__ rowstart,
                      const int* __restrict__ esrc, u16* __restrict__ out) {
    int lane = threadIdx.x & 63;
    int wid = threadIdx.x >> 6;
    int node = blockIdx.x * 4 + wid;
    if (node >= N_NODES) return;
    int half = lane >> 5;
    int li = lane & 31;
    int f0 = 2 * li;
    float sc0 = 1.f, sh0 = 0.f, sc1 = 1.f, sh1 = 0.f;
    if (sums != nullptr) {
        float inv = 1.0f / (float)N_NODES;
        float mu0 = sums[f0] * inv, mu1 = sums[f0 + 1] * inv;
        float v0 = fmaxf(sums[64 + f0] * inv - mu0 * mu0, 0.f);
        float v1 = fmaxf(sums[64 + f0 + 1] * inv - mu1 * mu1, 0.f);
        sc0 = g[f0] * rsqrtf(v0 + BN_EPS); sh0 = be[f0] - mu0 * sc0;
        sc1 = g[f0 + 1] * rsqrtf(v1 + BN_EPS); sh1 = be[f0 + 1] - mu1 * sc1;
    }
    float epsv = 1.0f + epsp[0];
    int e0 = rowstart[node], e1 = rowstart[node + 1];
    float s0 = 0.f, s1 = 0.f;
    for (int i = e0; i < e1; i += 64) {
        int cnt = min(e1 - i, 64);
        int src = (lane < cnt) ? esrc[i + lane] : 0;
        int j = 0;
        for (; j + 8 <= cnt; j += 8) {
            int a0 = __shfl(src, j + 0 + half);
            int a1 = __shfl(src, j + 2 + half);
            int a2 = __shfl(src, j + 4 + half);
            int a3 = __shfl(src, j + 6 + half);
            u32 b0 = *(const u32*)(hin + (size_t)a0 * 64 + f0);
            u32 b1 = *(const u32*)(hin + (size_t)a1 * 64 + f0);
            u32 b2 = *(const u32*)(hin + (size_t)a2 * 64 + f0);
            u32 b3 = *(const u32*)(hin + (size_t)a3 * 64 + f0);
            s0 += (bflo(b0) + bflo(b1)) + (bflo(b2) + bflo(b3));
            s1 += (bfhi(b0) + bfhi(b1)) + (bfhi(b2) + bfhi(b3));
        }
        for (; j < cnt; j += 2) {
            int jj = j + half;
            int a = __shfl(src, (jj < cnt) ? jj : (cnt - 1));  // clamp: valid+active src
            u32 b = *(const u32*)(hin + (size_t)a * 64 + f0);
            if (jj < cnt) { s0 += bflo(b); s1 += bfhi(b); }
        }
    }
    s0 += __shfl_xor(s0, 32);
    s1 += __shfl_xor(s1, 32);
    u32 sb = *(const u32*)(hin + (size_t)node * 64 + f0);
    float deg = (float)(e1 - e0);
    float o0 = sc0 * (s0 + epsv * bflo(sb)) + (deg + epsv) * sh0;
    float o1 = sc1 * (s1 + epsv * bfhi(sb)) + (deg + epsv) * sh1;
    if (half == 0) {
        u32 pk = (u32)f2bf(o0) | ((u32)f2bf(o1) << 16);
        *(u32*)(out + (size_t)node * 64 + f0) = pk;
    }
}

// ---------------- fused MLP via bf16 MFMA (unchanged from R5, passed) ----------------
__global__ __launch_bounds__(256) void k_mlp(
    const u16* __restrict__ A, const float* __restrict__ W1,
    const float* __restrict__ b1, const float* __restrict__ W2,
    const float* __restrict__ b2, u16* __restrict__ C, float* __restrict__ sums) {
    __shared__ u16 Wt1[64 * 72];
    __shared__ u16 Wt2[64 * 72];
    __shared__ u16 Hs[64 * 72];
    __shared__ float ssum[64];
    __shared__ float ssq[64];
    int tid = threadIdx.x;
    int r0 = blockIdx.x * 64;
    {
        int k = tid & 63;
        int cbase = tid >> 6;
        for (int c = cbase; c < 64; c += 4) {
            Wt1[c * 72 + k] = f2bf(W1[k * 64 + c]);
            Wt2[c * 72 + k] = f2bf(W2[k * 64 + c]);
        }
    }
    if (tid < 64) { ssum[tid] = 0.f; ssq[tid] = 0.f; }
    __syncthreads();

    int lane = tid & 63;
    int w = tid >> 6;
    int m = lane & 15;
    int q = lane >> 4;
    int rowg = r0 + w * 16 + m;
    int rowc = min(rowg, N_NODES - 1);

    bf16x8 a0 = *(const bf16x8*)(A + (size_t)rowc * 64 + q * 8);
    bf16x8 a1 = *(const bf16x8*)(A + (size_t)rowc * 64 + 32 + q * 8);
    f32x4 acc[4];
    #pragma unroll
    for (int c = 0; c < 4; ++c) {
        acc[c] = (f32x4){0.f, 0.f, 0.f, 0.f};
        bf16x8 bA = *(const bf16x8*)(&Wt1[(c * 16 + m) * 72 + q * 8]);
        bf16x8 bB = *(const bf16x8*)(&Wt1[(c * 16 + m) * 72 + 32 + q * 8]);
        acc[c] = __builtin_amdgcn_mfma_f32_16x16x32_bf16(a0, bA, acc[c], 0, 0, 0);
        acc[c] = __builtin_amdgcn_mfma_f32_16x16x32_bf16(a1, bB, acc[c], 0, 0, 0);
    }
    #pragma unroll
    for (int c = 0; c < 4; ++c) {
        int col = c * 16 + m;
        float bb = b1[col];
        #pragma unroll
        for (int r = 0; r < 4; ++r) {
            int rl = w * 16 + q * 4 + r;
            Hs[rl * 72 + col] = f2bf(fmaxf(acc[c][r] + bb, 0.f));
        }
    }
    bf16x8 h0 = *(const bf16x8*)(&Hs[(w * 16 + m) * 72 + q * 8]);
    bf16x8 h1 = *(const bf16x8*)(&Hs[(w * 16 + m) * 72 + 32 + q * 8]);
    f32x4 acc2[4];
    #pragma unroll
    for (int c = 0; c < 4; ++c) {
        acc2[c] = (f32x4){0.f, 0.f, 0.f, 0.f};
        bf16x8 bA = *(const bf16x8*)(&Wt2[(c * 16 + m) * 72 + q * 8]);
        bf16x8 bB = *(const bf16x8*)(&Wt2[(c * 16 + m) * 72 + 32 + q * 8]);
        acc2[c] = __builtin_amdgcn_mfma_f32_16x16x32_bf16(h0, bA, acc2[c], 0, 0, 0);
        acc2[c] = __builtin_amdgcn_mfma_f32_16x16x32_bf16(h1, bB, acc2[c], 0, 0, 0);
    }
    #pragma unroll
    for (int c = 0; c < 4; ++c) {
        int col = c * 16 + m;
        float bb = b2[col];
        float psum = 0.f, psq = 0.f;
        #pragma unroll
        for (int r = 0; r < 4; ++r) {
            int rg = r0 + w * 16 + q * 4 + r;
            if (rg < N_NODES) {
                float o = fmaxf(acc2[c][r] + bb, 0.f);
                C[(size_t)rg * 64 + col] = f2bf(o);
                psum += o;
                psq += o * o;
            }
        }
        atomicAdd(&ssum[col], psum);
        atomicAdd(&ssq[col], psq);
    }
    __syncthreads();
    if (tid < 64) {
        atomicAdd(&sums[tid], ssum[tid]);
        atomicAdd(&sums[64 + tid], ssq[tid]);
    }
}

// ---------------- pooling + FC + log_softmax ----------------
__global__ void k_pool(const u16* __restrict__ h, const float* __restrict__ sums,
                       const float* __restrict__ g4, const float* __restrict__ be4,
                       const int* __restrict__ gstart, const float* __restrict__ wfc,
                       const float* __restrict__ bfc, float* __restrict__ out) {
    __shared__ float smean[2][128];
    __shared__ float smax[2][128];
    __shared__ float lg[2][8];
    int tid = threadIdx.x;
    int lane = tid & 63;
    int w = tid >> 6;
    int gi = w >> 1;
    int part = w & 1;
    int gr = blockIdx.x * 2 + gi;
    int half = lane >> 5;
    int li = lane & 31;
    int f0 = 2 * li;
    float inv = 1.0f / (float)N_NODES;
    float mu0 = sums[f0] * inv, mu1 = sums[f0 + 1] * inv;
    float v0 = fmaxf(sums[64 + f0] * inv - mu0 * mu0, 0.f);
    float v1 = fmaxf(sums[64 + f0 + 1] * inv - mu1 * mu1, 0.f);
    float sc0 = g4[f0] * rsqrtf(v0 + BN_EPS), sh0 = be4[f0] - mu0 * sc0;
    float sc1 = g4[f0 + 1] * rsqrtf(v1 + BN_EPS), sh1 = be4[f0 + 1] - mu1 * sc1;
    int s0n = gstart[gr], s1n = gstart[gr + 1];
    int cnt = s1n - s0n;
    int mid = s0n + (cnt >> 1);
    int a = part ? mid : s0n;
    int b = part ? s1n : mid;
    float sum0 = 0.f, sum1 = 0.f, mx0 = -3.4e38f, mx1 = -3.4e38f;
    for (int n = a + half; n < b; n += 2) {
        u32 bits = *(const u32*)(h + (size_t)n * 64 + f0);
        float x0 = fmaf(bflo(bits), sc0, sh0);
        float x1 = fmaf(bfhi(bits), sc1, sh1);
        sum0 += x0; sum1 += x1;
        mx0 = fmaxf(mx0, x0); mx1 = fmaxf(mx1, x1);
    }
    sum0 += __shfl_xor(sum0, 32);
    sum1 += __shfl_xor(sum1, 32);
    mx0 = fmaxf(mx0, __shfl_xor(mx0, 32));
    mx1 = fmaxf(mx1, __shfl_xor(mx1, 32));
    if (half == 0 && part == 0) {
        smean[gi][f0] = sum0; smean[gi][f0 + 1] = sum1;
        smax[gi][f0] = mx0;   smax[gi][f0 + 1] = mx1;
    }
    __syncthreads();
    if (half == 0 && part == 1) {
        float m0 = fmaxf(smax[gi][f0], mx0), m1 = fmaxf(smax[gi][f0 + 1], mx1);
        float t0 = smean[gi][f0] + sum0, t1 = smean[gi][f0 + 1] + sum1;
        float fc = fmaxf((float)cnt, 1.f);
        smean[gi][f0] = t0 / fc;
        smean[gi][f0 + 1] = t1 / fc;
        smax[gi][f0] = (cnt > 0) ? m0 : 0.f;
        smax[gi][f0 + 1] = (cnt > 0) ? m1 : 0.f;
    }
    __syncthreads();
    if (part == 0 && lane < NCLASS) {
        float acc = bfc[lane];
        for (int j = 0; j < 64; ++j) acc = fmaf(smean[gi][j], wfc[j * NCLASS + lane], acc);
        for (int j = 0; j < 64; ++j) acc = fmaf(smax[gi][j], wfc[(64 + j) * NCLASS + lane], acc);
        lg[gi][lane] = acc;
    }
    __syncthreads();
    if (part == 0 && lane < NCLASS) {
        float mm = -3.4e38f;
        for (int c = 0; c < NCLASS; ++c) mm = fmaxf(mm, lg[gi][c]);
        float se = 0.f;
        for (int c = 0; c < NCLASS; ++c) se += expf(lg[gi][c] - mm);
        out[gr * NCLASS + lane] = lg[gi][lane] - mm - logf(se);
    }
}

// ---------------- launch ----------------

extern "C" void kernel_launch(void* const* d_in, const int* in_sizes, int n_in,
                              void* d_out, int out_size, void* d_ws, size_t ws_size,
                              hipStream_t stream) {
    const float* x = (const float*)d_in[0];
    const int* ei = (const int*)d_in[1];
    const int* batch = (const int*)d_in[2];
    const int* esrc_in = ei;
    const int* edst_in = ei + N_EDGES;

    const float* wa[4] = {(const float*)d_in[3], (const float*)d_in[7],
                          (const float*)d_in[11], (const float*)d_in[11]};
    const float* ba[4] = {(const float*)d_in[4], (const float*)d_in[8],
                          (const float*)d_in[12], (const float*)d_in[12]};
    const float* wb[4] = {(const float*)d_in[5], (const float*)d_in[9],
                          (const float*)d_in[13], (const float*)d_in[13]};
    const float* bb[4] = {(const float*)d_in[6], (const float*)d_in[10],
                          (const float*)d_in[14], (const float*)d_in[14]};
    const float* epsv[4] = {(const float*)d_in[15], (const float*)d_in[18],
                            (const float*)d_in[21], (const float*)d_in[24]};
    const float* gg[4] = {(const float*)d_in[16], (const float*)d_in[19],
                          (const float*)d_in[22], (const float*)d_in[25]};
    const float* bee[4] = {(const float*)d_in[17], (const float*)d_in[20],
                           (const float*)d_in[23], (const float*)d_in[26]};
    const float* wfc = (const float*)d_in[27];
    const float* bfc = (const float*)d_in[28];
    float* out = (float*)d_out;

    char* ws = (char*)d_ws;
    int* pairs = (int*)(ws + 0);               // 12,800,000 (dead after k_bsort)
    u16* bufA = (u16*)(ws + 0);                // alias of pairs
    int* esrc = (int*)(ws + 12800000);         // 12,800,000
    u16* xb = (u16*)(ws + 25600000);           // 12,800,000
    u16* bufB = (u16*)(ws + 38400000);         // 12,800,000
    int* rowstart = (int*)(ws + 51200000);     // 400,128
    int* blockhist = (int*)(ws + 51600128);    // 391*391*4 = 611,524 -> pad 612,352
    int* colsum = (int*)(ws + 52212480);       // 2,048
    int* bstart = (int*)(ws + 52214528);       // 2,048
    int* gstart = (int*)(ws + 52216576);       // 513 ints -> pad 2,560
    float* sumsL = (float*)(ws + 52219136);    // 4 layers x 128 f32 = 2,048
    // total: 52,221,184 bytes

    hipMemsetAsync(ws + 52219136, 0, 2048, stream);   // sumsL only

    k_cast<<<(N_NODES * 64 / 4 + 255) / 256, 256, 0, stream>>>(x, xb);
    k_hist<<<EB + NBLK_NODE, 256, 0, stream>>>(edst_in, batch, blockhist, gstart);
    k_scan_cols<<<NBUCK, 512, 0, stream>>>(blockhist, colsum);
    k_scan_b<<<1, 512, 0, stream>>>(colsum, bstart, rowstart);
    k_bscatter<<<EB, 256, 0, stream>>>(esrc_in, edst_in, bstart, blockhist, pairs);
    k_bsort<<<NBUCK, 256, 0, stream>>>(pairs, bstart, rowstart, esrc);

    const int AGG_GRID = (N_NODES + 3) / 4;
    const int MLP_GRID = (N_NODES + 63) / 64;
    for (int L = 0; L < 4; ++L) {
        const u16* hin = (L == 0) ? xb : bufB;
        const float* sp = (L == 0) ? nullptr : (sumsL + (L - 1) * 128);
        const float* gp = (L == 0) ? gg[0] : gg[L - 1];
        const float* bp = (L == 0) ? bee[0] : bee[L - 1];
        k_agg<<<AGG_GRID, 256, 0, stream>>>(hin, sp, gp, bp, epsv[L], rowstart,
                                            esrc, bufA);
        k_mlp<<<MLP_GRID, 256, 0, stream>>>(bufA, wa[L], ba[L], wb[L], bb[L],
                                            bufB, sumsL + L * 128);
    }

    k_pool<<<NGRAPH / 2, 256, 0, stream>>>(bufB, sumsL + 3 * 128, gg[3], bee[3],
                                           gstart, wfc, bfc, out);
}

// Round 7
// 635.842 us; speedup vs baseline: 2.2965x; 1.2348x over previous
//
#include <hip/hip_runtime.h>

#define N_NODES 100000
#define N_EDGES 3200000
#define NGRAPH 512
#define NCLASS 6
#define BN_EPS 1e-5f

#define BSHIFT 8
#define NBUCK 391          // ceil(100000 / 256)
#define CHUNK 8192         // edges per block in bucket passes
#define EB 391             // ceil(N_EDGES / CHUNK)
#define NBLK_NODE 391      // ceil(N_NODES / 256)
#define MLPG 1563          // ceil(N_NODES / 64) = k_mlp grid = #partials rows

typedef unsigned short u16;
typedef unsigned int u32;
typedef __attribute__((ext_vector_type(8))) short bf16x8;
typedef __attribute__((ext_vector_type(4))) float f32x4;

__device__ __forceinline__ float bflo(u32 b) {
    u32 t = b << 16; return __builtin_bit_cast(float, t);
}
__device__ __forceinline__ float bfhi(u32 b) {
    u32 t = b & 0xffff0000u; return __builtin_bit_cast(float, t);
}
__device__ __forceinline__ u16 f2bf(float f) {   // round-to-nearest-even
    u32 u = __builtin_bit_cast(u32, f);
    return (u16)((u + 0x7fffu + ((u >> 16) & 1u)) >> 16);
}

// ---------------- input cast: x fp32 -> bf16 ----------------
__global__ void k_cast(const float* __restrict__ x, u16* __restrict__ xb) {
    int base = (blockIdx.x * 256 + threadIdx.x) * 4;
    if (base < N_NODES * 64) {
        float4 v = *(const float4*)(x + base);
        ushort4 o = make_ushort4(f2bf(v.x), f2bf(v.y), f2bf(v.z), f2bf(v.w));
        *(ushort4*)(xb + base) = o;
    }
}

// ---------------- one-shot weight prep + identity ss0 ----------------
// Converts 6 unique W[64][64] fp32 -> bf16 transposed padded: Wt[c*72+k].
// Done ONCE instead of per-mlp-block (R6: 1563 blocks x stride-256B gathers).
__global__ void k_prep(const float* __restrict__ W10, const float* __restrict__ W20,
                       const float* __restrict__ W11, const float* __restrict__ W21,
                       const float* __restrict__ W12, const float* __restrict__ W22,
                       u16* __restrict__ Wtg, float* __restrict__ ss0) {
    int b = blockIdx.x;
    int t = threadIdx.x;
    if (b < 96) {
        int e = b * 256 + t;          // < 24576 = 6 * 4096
        int mat = e >> 12;
        int i = e & 4095;
        const float* s = (mat == 0) ? W10 : (mat == 1) ? W20 : (mat == 2) ? W11
                       : (mat == 3) ? W21 : (mat == 4) ? W12 : W22;
        float v = s[i];
        int k = i >> 6, c = i & 63;
        Wtg[mat * 4608 + c * 72 + k] = f2bf(v);
    } else {
        if (t < 64) ss0[t] = 1.0f;
        else if (t < 128) ss0[t] = 0.0f;
    }
}

// ---------------- CSR build ----------------

// blocks [0,EB): per-block coarse hist of dst>>8 -> blockhist[b][k].
// blocks [EB,EB+NBLK_NODE): gstart via boundary detection on sorted batch (no atomics).
__global__ void k_hist(const int* __restrict__ dst, const int* __restrict__ batch,
                       int* __restrict__ blockhist, int* __restrict__ gstart) {
    __shared__ int hist[NBUCK];
    int tid = threadIdx.x;
    int b = blockIdx.x;
    if (b < EB) {
        long e0 = (long)b * CHUNK;
        for (int i = tid; i < NBUCK; i += 256) hist[i] = 0;
        __syncthreads();
        for (int i = tid; i < CHUNK; i += 256) {
            long e = e0 + i;
            if (e < N_EDGES) atomicAdd(&hist[dst[e] >> BSHIFT], 1);
        }
        __syncthreads();
        for (int i = tid; i < NBUCK; i += 256) blockhist[b * NBUCK + i] = hist[i];
    } else {
        int i = (b - EB) * 256 + tid;
        if (i < N_NODES) {
            int bi = batch[i];
            int bp = (i == 0) ? -1 : batch[i - 1];
            for (int g = bp + 1; g <= bi; ++g) gstart[g] = i;
            if (i == N_NODES - 1)
                for (int g = bi + 1; g <= NGRAPH; ++g) gstart[g] = N_NODES;
        }
    }
}

// one block per bucket k: exclusive-scan blockhist column k (in place) + total.
__global__ void k_scan_cols(int* __restrict__ blockhist, int* __restrict__ colsum) {
    __shared__ int sh[512];
    int k = blockIdx.x;
    int t = threadIdx.x;
    int v = (t < EB) ? blockhist[t * NBUCK + k] : 0;
    sh[t] = v;
    __syncthreads();
    for (int off = 1; off < 512; off <<= 1) {
        int x = (t >= off) ? sh[t - off] : 0;
        __syncthreads();
        sh[t] += x;
        __syncthreads();
    }
    if (t < EB) blockhist[t * NBUCK + k] = sh[t] - v;
    if (t == 511) colsum[k] = sh[511];
}

// single block: scan bucket totals -> bstart; set rowstart[N]
__global__ void k_scan_b(const int* __restrict__ colsum, int* __restrict__ bstart,
                         int* __restrict__ rowstart) {
    __shared__ int sh[512];
    int t = threadIdx.x;
    int v = (t < NBUCK) ? colsum[t] : 0;
    sh[t] = v;
    __syncthreads();
    for (int off = 1; off < 512; off <<= 1) {
        int x = (t >= off) ? sh[t - off] : 0;
        __syncthreads();
        sh[t] += x;
        __syncthreads();
    }
    if (t < NBUCK) bstart[t] = sh[t] - v;
    if (t == NBUCK - 1) bstart[NBUCK] = sh[t];
    if (t == 0) rowstart[N_NODES] = N_EDGES;
}

// scatter packed (src<<8 | dst&255) using precomputed per-block bases.
__global__ void k_bscatter(const int* __restrict__ src, const int* __restrict__ dst,
                           const int* __restrict__ bstart,
                           const int* __restrict__ blockhist, int* __restrict__ pairs) {
    __shared__ int base[NBUCK];
    __shared__ int hist[NBUCK];
    int tid = threadIdx.x;
    int b = blockIdx.x;
    long e0 = (long)b * CHUNK;
    for (int k = tid; k < NBUCK; k += 256) {
        base[k] = bstart[k] + blockhist[b * NBUCK + k];
        hist[k] = 0;
    }
    __syncthreads();
    for (int i = tid; i < CHUNK; i += 256) {
        long e = e0 + i;
        if (e < N_EDGES) {
            int d = dst[e];
            int k = d >> BSHIFT;
            int r = atomicAdd(&hist[k], 1);
            pairs[base[k] + r] = (src[e] << 8) | (d & 255);
        }
    }
}

// per-bucket fine counting sort -> rowstart, esrc
__global__ void k_bsort(const int* __restrict__ pairs, const int* __restrict__ bstart,
                        int* __restrict__ rowstart, int* __restrict__ esrc) {
    __shared__ int deg[256];
    __shared__ int cur[256];
    int b = blockIdx.x;
    int tid = threadIdx.x;
    int p0 = bstart[b], p1 = bstart[b + 1];
    deg[tid] = 0;
    __syncthreads();
    for (int i = p0 + tid; i < p1; i += 256)
        atomicAdd(&deg[pairs[i] & 255], 1);
    __syncthreads();
    int v = deg[tid];
    cur[tid] = v;
    __syncthreads();
    for (int off = 1; off < 256; off <<= 1) {
        int x = (tid >= off) ? cur[tid - off] : 0;
        __syncthreads();
        cur[tid] += x;
        __syncthreads();
    }
    int excl = cur[tid] - v;
    int node = (b << BSHIFT) + tid;
    if (node < N_NODES) rowstart[node] = p0 + excl;
    __syncthreads();
    cur[tid] = excl;
    __syncthreads();
    for (int i = p0 + tid; i < p1; i += 256) {
        u32 pr = (u32)pairs[i];
        int r = atomicAdd(&cur[pr & 255], 1);
        esrc[p0 + r] = (int)(pr >> 8);
    }
}

// ---------------- BN fold: reduce partials -> scale/shift ----------------
// 64 blocks; block f reduces columns f (sum) and 64+f (sumsq) over MLPG rows.
__global__ void k_bn(const float* __restrict__ partials, const float* __restrict__ g,
                     const float* __restrict__ be, float* __restrict__ ss) {
    __shared__ float sS[256];
    __shared__ float sQ[256];
    int f = blockIdx.x;
    int t = threadIdx.x;
    float aS = 0.f, aQ = 0.f;
    for (int b = t; b < MLPG; b += 256) {
        aS += partials[b * 128 + f];
        aQ += partials[b * 128 + 64 + f];
    }
    sS[t] = aS; sQ[t] = aQ;
    __syncthreads();
    for (int off = 128; off >= 1; off >>= 1) {
        if (t < off) { sS[t] += sS[t + off]; sQ[t] += sQ[t + off]; }
        __syncthreads();
    }
    if (t == 0) {
        float mu = sS[0] / (float)N_NODES;
        float var = fmaxf(sQ[0] / (float)N_NODES - mu * mu, 0.f);
        float sc = g[f] * rsqrtf(var + BN_EPS);
        ss[f] = sc;
        ss[64 + f] = be[f] - mu * sc;
    }
}

// ---------------- aggregation (bf16 in/out, folded BN scale/shift) ----------------
__global__ void k_agg(const u16* __restrict__ hin, const float* __restrict__ ss,
                      const float* __restrict__ epsp, const int* __restrict__ rowstart,
                      const int* __restrict__ esrc, u16* __restrict__ out) {
    int lane = threadIdx.x & 63;
    int wid = threadIdx.x >> 6;
    int node = blockIdx.x * 4 + wid;
    if (node >= N_NODES) return;
    int half = lane >> 5;
    int li = lane & 31;
    int f0 = 2 * li;
    float sc0 = ss[f0], sc1 = ss[f0 + 1];
    float sh0 = ss[64 + f0], sh1 = ss[64 + f0 + 1];
    float epsv = 1.0f + epsp[0];
    int e0 = rowstart[node], e1 = rowstart[node + 1];
    float s0 = 0.f, s1 = 0.f;
    for (int i = e0; i < e1; i += 64) {
        int cnt = min(e1 - i, 64);
        int src = (lane < cnt) ? esrc[i + lane] : 0;
        int j = 0;
        for (; j + 8 <= cnt; j += 8) {
            int a0 = __shfl(src, j + 0 + half);
            int a1 = __shfl(src, j + 2 + half);
            int a2 = __shfl(src, j + 4 + half);
            int a3 = __shfl(src, j + 6 + half);
            u32 b0 = *(const u32*)(hin + (size_t)a0 * 64 + f0);
            u32 b1 = *(const u32*)(hin + (size_t)a1 * 64 + f0);
            u32 b2 = *(const u32*)(hin + (size_t)a2 * 64 + f0);
            u32 b3 = *(const u32*)(hin + (size_t)a3 * 64 + f0);
            s0 += (bflo(b0) + bflo(b1)) + (bflo(b2) + bflo(b3));
            s1 += (bfhi(b0) + bfhi(b1)) + (bfhi(b2) + bfhi(b3));
        }
        for (; j < cnt; j += 2) {
            int jj = j + half;
            int a = __shfl(src, (jj < cnt) ? jj : (cnt - 1));  // clamp: valid+active src
            u32 b = *(const u32*)(hin + (size_t)a * 64 + f0);
            if (jj < cnt) { s0 += bflo(b); s1 += bfhi(b); }
        }
    }
    s0 += __shfl_xor(s0, 32);
    s1 += __shfl_xor(s1, 32);
    u32 sb = *(const u32*)(hin + (size_t)node * 64 + f0);
    float deg = (float)(e1 - e0);
    float o0 = sc0 * (s0 + epsv * bflo(sb)) + (deg + epsv) * sh0;
    float o1 = sc1 * (s1 + epsv * bfhi(sb)) + (deg + epsv) * sh1;
    if (half == 0) {
        u32 pk = (u32)f2bf(o0) | ((u32)f2bf(o1) << 16);
        *(u32*)(out + (size_t)node * 64 + f0) = pk;
    }
}

// ---------------- fused MLP via bf16 MFMA ----------------
// Weight staging: contiguous 18432B int4 copy of pre-transposed bf16 weights.
// Stats: per-block coalesced stores to partials[block][128] (NO global atomics
// — R6's 76us k_mlp was a 1563-deep same-line cross-XCD atomic chain).
__global__ __launch_bounds__(256) void k_mlp(
    const u16* __restrict__ A, const u16* __restrict__ Wtg,
    const float* __restrict__ b1, const float* __restrict__ b2,
    u16* __restrict__ C, float* __restrict__ partials) {
    __shared__ __align__(16) u16 Wts[9216];   // Wt1[64*72] then Wt2[64*72]
    __shared__ __align__(16) u16 Hs[64 * 72];
    __shared__ float ssum[64];
    __shared__ float ssq[64];
    int tid = threadIdx.x;
    int r0 = blockIdx.x * 64;
    {
        const int4* srcp = (const int4*)Wtg;
        int4* dstp = (int4*)Wts;
        for (int i = tid; i < 1152; i += 256) dstp[i] = srcp[i];
    }
    if (tid < 64) { ssum[tid] = 0.f; ssq[tid] = 0.f; }
    __syncthreads();
    const u16* Wt1 = Wts;
    const u16* Wt2 = Wts + 4608;

    int lane = tid & 63;
    int w = tid >> 6;
    int m = lane & 15;
    int q = lane >> 4;
    int rowg = r0 + w * 16 + m;
    int rowc = min(rowg, N_NODES - 1);

    bf16x8 a0 = *(const bf16x8*)(A + (size_t)rowc * 64 + q * 8);
    bf16x8 a1 = *(const bf16x8*)(A + (size_t)rowc * 64 + 32 + q * 8);
    f32x4 acc[4];
    #pragma unroll
    for (int c = 0; c < 4; ++c) {
        acc[c] = (f32x4){0.f, 0.f, 0.f, 0.f};
        bf16x8 bA = *(const bf16x8*)(&Wt1[(c * 16 + m) * 72 + q * 8]);
        bf16x8 bB = *(const bf16x8*)(&Wt1[(c * 16 + m) * 72 + 32 + q * 8]);
        acc[c] = __builtin_amdgcn_mfma_f32_16x16x32_bf16(a0, bA, acc[c], 0, 0, 0);
        acc[c] = __builtin_amdgcn_mfma_f32_16x16x32_bf16(a1, bB, acc[c], 0, 0, 0);
    }
    #pragma unroll
    for (int c = 0; c < 4; ++c) {
        int col = c * 16 + m;
        float bb = b1[col];
        #pragma unroll
        for (int r = 0; r < 4; ++r) {
            int rl = w * 16 + q * 4 + r;
            Hs[rl * 72 + col] = f2bf(fmaxf(acc[c][r] + bb, 0.f));
        }
    }
    bf16x8 h0 = *(const bf16x8*)(&Hs[(w * 16 + m) * 72 + q * 8]);
    bf16x8 h1 = *(const bf16x8*)(&Hs[(w * 16 + m) * 72 + 32 + q * 8]);
    f32x4 acc2[4];
    #pragma unroll
    for (int c = 0; c < 4; ++c) {
        acc2[c] = (f32x4){0.f, 0.f, 0.f, 0.f};
        bf16x8 bA = *(const bf16x8*)(&Wt2[(c * 16 + m) * 72 + q * 8]);
        bf16x8 bB = *(const bf16x8*)(&Wt2[(c * 16 + m) * 72 + 32 + q * 8]);
        acc2[c] = __builtin_amdgcn_mfma_f32_16x16x32_bf16(h0, bA, acc2[c], 0, 0, 0);
        acc2[c] = __builtin_amdgcn_mfma_f32_16x16x32_bf16(h1, bB, acc2[c], 0, 0, 0);
    }
    #pragma unroll
    for (int c = 0; c < 4; ++c) {
        int col = c * 16 + m;
        float bb = b2[col];
        float psum = 0.f, psq = 0.f;
        #pragma unroll
        for (int r = 0; r < 4; ++r) {
            int rg = r0 + w * 16 + q * 4 + r;
            if (rg < N_NODES) {
                float o = fmaxf(acc2[c][r] + bb, 0.f);
                C[(size_t)rg * 64 + col] = f2bf(o);
                psum += o;
                psq += o * o;
            }
        }
        atomicAdd(&ssum[col], psum);
        atomicAdd(&ssq[col], psq);
    }
    __syncthreads();
    if (tid < 128) {
        float v = (tid < 64) ? ssum[tid] : ssq[tid - 64];
        partials[(size_t)blockIdx.x * 128 + tid] = v;
    }
}

// ---------------- pooling + FC + log_softmax ----------------
__global__ void k_pool(const u16* __restrict__ h, const float* __restrict__ ss,
                       const int* __restrict__ gstart, const float* __restrict__ wfc,
                       const float* __restrict__ bfc, float* __restrict__ out) {
    __shared__ float smean[2][128];
    __shared__ float smax[2][128];
    __shared__ float lg[2][8];
    int tid = threadIdx.x;
    int lane = tid & 63;
    int w = tid >> 6;
    int gi = w >> 1;
    int part = w & 1;
    int gr = blockIdx.x * 2 + gi;
    int half = lane >> 5;
    int li = lane & 31;
    int f0 = 2 * li;
    float sc0 = ss[f0], sc1 = ss[f0 + 1];
    float sh0 = ss[64 + f0], sh1 = ss[64 + f0 + 1];
    int s0n = gstart[gr], s1n = gstart[gr + 1];
    int cnt = s1n - s0n;
    int mid = s0n + (cnt >> 1);
    int a = part ? mid : s0n;
    int b = part ? s1n : mid;
    float sum0 = 0.f, sum1 = 0.f, mx0 = -3.4e38f, mx1 = -3.4e38f;
    for (int n = a + half; n < b; n += 2) {
        u32 bits = *(const u32*)(h + (size_t)n * 64 + f0);
        float x0 = fmaf(bflo(bits), sc0, sh0);
        float x1 = fmaf(bfhi(bits), sc1, sh1);
        sum0 += x0; sum1 += x1;
        mx0 = fmaxf(mx0, x0); mx1 = fmaxf(mx1, x1);
    }
    sum0 += __shfl_xor(sum0, 32);
    sum1 += __shfl_xor(sum1, 32);
    mx0 = fmaxf(mx0, __shfl_xor(mx0, 32));
    mx1 = fmaxf(mx1, __shfl_xor(mx1, 32));
    if (half == 0 && part == 0) {
        smean[gi][f0] = sum0; smean[gi][f0 + 1] = sum1;
        smax[gi][f0] = mx0;   smax[gi][f0 + 1] = mx1;
    }
    __syncthreads();
    if (half == 0 && part == 1) {
        float m0 = fmaxf(smax[gi][f0], mx0), m1 = fmaxf(smax[gi][f0 + 1], mx1);
        float t0 = smean[gi][f0] + sum0, t1 = smean[gi][f0 + 1] + sum1;
        float fc = fmaxf((float)cnt, 1.f);
        smean[gi][f0] = t0 / fc;
        smean[gi][f0 + 1] = t1 / fc;
        smax[gi][f0] = (cnt > 0) ? m0 : 0.f;
        smax[gi][f0 + 1] = (cnt > 0) ? m1 : 0.f;
    }
    __syncthreads();
    if (part == 0 && lane < NCLASS) {
        float acc = bfc[lane];
        for (int j = 0; j < 64; ++j) acc = fmaf(smean[gi][j], wfc[j * NCLASS + lane], acc);
        for (int j = 0; j < 64; ++j) acc = fmaf(smax[gi][j], wfc[(64 + j) * NCLASS + lane], acc);
        lg[gi][lane] = acc;
    }
    __syncthreads();
    if (part == 0 && lane < NCLASS) {
        float mm = -3.4e38f;
        for (int c = 0; c < NCLASS; ++c) mm = fmaxf(mm, lg[gi][c]);
        float se = 0.f;
        for (int c = 0; c < NCLASS; ++c) se += expf(lg[gi][c] - mm);
        out[gr * NCLASS + lane] = lg[gi][lane] - mm - logf(se);
    }
}

// ---------------- launch ----------------

extern "C" void kernel_launch(void* const* d_in, const int* in_sizes, int n_in,
                              void* d_out, int out_size, void* d_ws, size_t ws_size,
                              hipStream_t stream) {
    const float* x = (const float*)d_in[0];
    const int* ei = (const int*)d_in[1];
    const int* batch = (const int*)d_in[2];
    const int* esrc_in = ei;
    const int* edst_in = ei + N_EDGES;

    const float* ba[4] = {(const float*)d_in[4], (const float*)d_in[8],
                          (const float*)d_in[12], (const float*)d_in[12]};
    const float* bb[4] = {(const float*)d_in[6], (const float*)d_in[10],
                          (const float*)d_in[14], (const float*)d_in[14]};
    const float* epsv[4] = {(const float*)d_in[15], (const float*)d_in[18],
                            (const float*)d_in[21], (const float*)d_in[24]};
    const float* gg[4] = {(const float*)d_in[16], (const float*)d_in[19],
                          (const float*)d_in[22], (const float*)d_in[25]};
    const float* bee[4] = {(const float*)d_in[17], (const float*)d_in[20],
                           (const float*)d_in[23], (const float*)d_in[26]};
    const float* wfc = (const float*)d_in[27];
    const float* bfc = (const float*)d_in[28];
    float* out = (float*)d_out;

    char* ws = (char*)d_ws;
    int* pairs = (int*)(ws + 0);               // 12,800,000 (dead after k_bsort)
    u16* bufA = (u16*)(ws + 0);                // alias of pairs
    int* esrc = (int*)(ws + 12800000);         // 12,800,000
    u16* xb = (u16*)(ws + 25600000);           // 12,800,000
    u16* bufB = (u16*)(ws + 38400000);         // 12,800,000
    int* rowstart = (int*)(ws + 51200000);     // 400,128
    int* blockhist = (int*)(ws + 51600128);    // 612,352 (padded)
    int* colsum = (int*)(ws + 52212480);       // 2,048
    int* bstart = (int*)(ws + 52214528);       // 2,048
    int* gstart = (int*)(ws + 52216576);       // 2,560
    float* partials = (float*)(ws + 52219136); // 1563*128*4 = 800,256 -> pad 800,768
    float* ssbuf = (float*)(ws + 53019904);    // 5*128*4 = 2,560
    u16* Wtg = (u16*)(ws + 53022464);          // 6*4608*2 = 55,296
    // total: 53,077,760 bytes; no memsets needed (all buffers fully written)

    k_cast<<<(N_NODES * 64 / 4 + 255) / 256, 256, 0, stream>>>(x, xb);
    k_prep<<<97, 256, 0, stream>>>((const float*)d_in[3], (const float*)d_in[5],
                                   (const float*)d_in[7], (const float*)d_in[9],
                                   (const float*)d_in[11], (const float*)d_in[13],
                                   Wtg, ssbuf);
    k_hist<<<EB + NBLK_NODE, 256, 0, stream>>>(edst_in, batch, blockhist, gstart);
    k_scan_cols<<<NBUCK, 512, 0, stream>>>(blockhist, colsum);
    k_scan_b<<<1, 512, 0, stream>>>(colsum, bstart, rowstart);
    k_bscatter<<<EB, 256, 0, stream>>>(esrc_in, edst_in, bstart, blockhist, pairs);
    k_bsort<<<NBUCK, 256, 0, stream>>>(pairs, bstart, rowstart, esrc);

    const int AGG_GRID = (N_NODES + 3) / 4;
    for (int L = 0; L < 4; ++L) {
        const u16* hin = (L == 0) ? xb : bufB;
        const u16* wt = Wtg + (size_t)((L < 2) ? L : 2) * 9216;
        k_agg<<<AGG_GRID, 256, 0, stream>>>(hin, ssbuf + L * 128, epsv[L], rowstart,
                                            esrc, bufA);
        k_mlp<<<MLPG, 256, 0, stream>>>(bufA, wt, ba[L], bb[L], bufB, partials);
        k_bn<<<64, 256, 0, stream>>>(partials, gg[L], bee[L], ssbuf + (L + 1) * 128);
    }

    k_pool<<<NGRAPH / 2, 256, 0, stream>>>(bufB, ssbuf + 4 * 128, gstart, wfc, bfc, out);
}

// Round 8
// 615.117 us; speedup vs baseline: 2.3739x; 1.0337x over previous
//
#include <hip/hip_runtime.h>

#define N_NODES 100000
#define N_EDGES 3200000
#define NGRAPH 512
#define NCLASS 6
#define BN_EPS 1e-5f

#define BSHIFT 8
#define NBUCK 391          // ceil(100000 / 256)
#define CHUNK 8192         // edges per block in bucket passes
#define EB 391             // ceil(N_EDGES / CHUNK)
#define NBLK_NODE 391      // ceil(N_NODES / 256)
#define MLPG 1563          // ceil(N_NODES / 64) = k_mlp grid = #partials rows

typedef unsigned short u16;
typedef unsigned int u32;
typedef __attribute__((ext_vector_type(8))) short bf16x8;
typedef __attribute__((ext_vector_type(4))) float f32x4;

__device__ __forceinline__ float bflo(u32 b) {
    u32 t = b << 16; return __builtin_bit_cast(float, t);
}
__device__ __forceinline__ float bfhi(u32 b) {
    u32 t = b & 0xffff0000u; return __builtin_bit_cast(float, t);
}
__device__ __forceinline__ u16 f2bf(float f) {   // round-to-nearest-even
    u32 u = __builtin_bit_cast(u32, f);
    return (u16)((u + 0x7fffu + ((u >> 16) & 1u)) >> 16);
}

// ---------------- input cast: x fp32 -> bf16 ----------------
__global__ void k_cast(const float* __restrict__ x, u16* __restrict__ xb) {
    int base = (blockIdx.x * 256 + threadIdx.x) * 4;
    if (base < N_NODES * 64) {
        float4 v = *(const float4*)(x + base);
        ushort4 o = make_ushort4(f2bf(v.x), f2bf(v.y), f2bf(v.z), f2bf(v.w));
        *(ushort4*)(xb + base) = o;
    }
}

// ---------------- one-shot weight prep + identity ss0 ----------------
__global__ void k_prep(const float* __restrict__ W10, const float* __restrict__ W20,
                       const float* __restrict__ W11, const float* __restrict__ W21,
                       const float* __restrict__ W12, const float* __restrict__ W22,
                       u16* __restrict__ Wtg, float* __restrict__ ss0) {
    int b = blockIdx.x;
    int t = threadIdx.x;
    if (b < 96) {
        int e = b * 256 + t;          // < 24576 = 6 * 4096
        int mat = e >> 12;
        int i = e & 4095;
        const float* s = (mat == 0) ? W10 : (mat == 1) ? W20 : (mat == 2) ? W11
                       : (mat == 3) ? W21 : (mat == 4) ? W12 : W22;
        float v = s[i];
        int k = i >> 6, c = i & 63;
        Wtg[mat * 4608 + c * 72 + k] = f2bf(v);
    } else {
        if (t < 64) ss0[t] = 1.0f;
        else if (t < 128) ss0[t] = 0.0f;
    }
}

// ---------------- CSR build ----------------

// blocks [0,EB): per-block coarse hist of dst>>8 -> blockhist[b][k].
// blocks [EB,EB+NBLK_NODE): gstart via boundary detection on sorted batch (no atomics).
__global__ void k_hist(const int* __restrict__ dst, const int* __restrict__ batch,
                       int* __restrict__ blockhist, int* __restrict__ gstart) {
    __shared__ int hist[NBUCK];
    int tid = threadIdx.x;
    int b = blockIdx.x;
    if (b < EB) {
        long e0 = (long)b * CHUNK;
        for (int i = tid; i < NBUCK; i += 256) hist[i] = 0;
        __syncthreads();
        for (int i = tid; i < CHUNK; i += 256) {
            long e = e0 + i;
            if (e < N_EDGES) atomicAdd(&hist[dst[e] >> BSHIFT], 1);
        }
        __syncthreads();
        for (int i = tid; i < NBUCK; i += 256) blockhist[b * NBUCK + i] = hist[i];
    } else {
        int i = (b - EB) * 256 + tid;
        if (i < N_NODES) {
            int bi = batch[i];
            int bp = (i == 0) ? -1 : batch[i - 1];
            for (int g = bp + 1; g <= bi; ++g) gstart[g] = i;
            if (i == N_NODES - 1)
                for (int g = bi + 1; g <= NGRAPH; ++g) gstart[g] = N_NODES;
        }
    }
}

// one block per bucket k: exclusive-scan blockhist column k (in place) + total.
__global__ void k_scan_cols(int* __restrict__ blockhist, int* __restrict__ colsum) {
    __shared__ int sh[512];
    int k = blockIdx.x;
    int t = threadIdx.x;
    int v = (t < EB) ? blockhist[t * NBUCK + k] : 0;
    sh[t] = v;
    __syncthreads();
    for (int off = 1; off < 512; off <<= 1) {
        int x = (t >= off) ? sh[t - off] : 0;
        __syncthreads();
        sh[t] += x;
        __syncthreads();
    }
    if (t < EB) blockhist[t * NBUCK + k] = sh[t] - v;
    if (t == 511) colsum[k] = sh[511];
}

// single block: scan bucket totals -> bstart; set rowstart[N]
__global__ void k_scan_b(const int* __restrict__ colsum, int* __restrict__ bstart,
                         int* __restrict__ rowstart) {
    __shared__ int sh[512];
    int t = threadIdx.x;
    int v = (t < NBUCK) ? colsum[t] : 0;
    sh[t] = v;
    __syncthreads();
    for (int off = 1; off < 512; off <<= 1) {
        int x = (t >= off) ? sh[t - off] : 0;
        __syncthreads();
        sh[t] += x;
        __syncthreads();
    }
    if (t < NBUCK) bstart[t] = sh[t] - v;
    if (t == NBUCK - 1) bstart[NBUCK] = sh[t];
    if (t == 0) rowstart[N_NODES] = N_EDGES;
}

// scatter packed (src<<8 | dst&255) using precomputed per-block bases.
__global__ void k_bscatter(const int* __restrict__ src, const int* __restrict__ dst,
                           const int* __restrict__ bstart,
                           const int* __restrict__ blockhist, int* __restrict__ pairs) {
    __shared__ int base[NBUCK];
    __shared__ int hist[NBUCK];
    int tid = threadIdx.x;
    int b = blockIdx.x;
    long e0 = (long)b * CHUNK;
    for (int k = tid; k < NBUCK; k += 256) {
        base[k] = bstart[k] + blockhist[b * NBUCK + k];
        hist[k] = 0;
    }
    __syncthreads();
    for (int i = tid; i < CHUNK; i += 256) {
        long e = e0 + i;
        if (e < N_EDGES) {
            int d = dst[e];
            int k = d >> BSHIFT;
            int r = atomicAdd(&hist[k], 1);
            pairs[base[k] + r] = (src[e] << 8) | (d & 255);
        }
    }
}

// per-bucket fine counting sort -> rowstart, esrc
__global__ void k_bsort(const int* __restrict__ pairs, const int* __restrict__ bstart,
                        int* __restrict__ rowstart, int* __restrict__ esrc) {
    __shared__ int deg[256];
    __shared__ int cur[256];
    int b = blockIdx.x;
    int tid = threadIdx.x;
    int p0 = bstart[b], p1 = bstart[b + 1];
    deg[tid] = 0;
    __syncthreads();
    for (int i = p0 + tid; i < p1; i += 256)
        atomicAdd(&deg[pairs[i] & 255], 1);
    __syncthreads();
    int v = deg[tid];
    cur[tid] = v;
    __syncthreads();
    for (int off = 1; off < 256; off <<= 1) {
        int x = (tid >= off) ? cur[tid - off] : 0;
        __syncthreads();
        cur[tid] += x;
        __syncthreads();
    }
    int excl = cur[tid] - v;
    int node = (b << BSHIFT) + tid;
    if (node < N_NODES) rowstart[node] = p0 + excl;
    __syncthreads();
    cur[tid] = excl;
    __syncthreads();
    for (int i = p0 + tid; i < p1; i += 256) {
        u32 pr = (u32)pairs[i];
        int r = atomicAdd(&cur[pr & 255], 1);
        esrc[p0 + r] = (int)(pr >> 8);
    }
}

// ---------------- BN fold: reduce partials -> scale/shift ----------------
__global__ void k_bn(const float* __restrict__ partials, const float* __restrict__ g,
                     const float* __restrict__ be, float* __restrict__ ss) {
    __shared__ float sS[256];
    __shared__ float sQ[256];
    int f = blockIdx.x;
    int t = threadIdx.x;
    float aS = 0.f, aQ = 0.f;
    for (int b = t; b < MLPG; b += 256) {
        aS += partials[b * 128 + f];
        aQ += partials[b * 128 + 64 + f];
    }
    sS[t] = aS; sQ[t] = aQ;
    __syncthreads();
    for (int off = 128; off >= 1; off >>= 1) {
        if (t < off) { sS[t] += sS[t + off]; sQ[t] += sQ[t + off]; }
        __syncthreads();
    }
    if (t == 0) {
        float mu = sS[0] / (float)N_NODES;
        float var = fmaxf(sQ[0] / (float)N_NODES - mu * mu, 0.f);
        float sc = g[f] * rsqrtf(var + BN_EPS);
        ss[f] = sc;
        ss[64 + f] = be[f] - mu * sc;
    }
}

// ---------------- aggregation: 8 rows per dwordx4 gather ----------------
// One wave per dst node. Lane group g=lane>>3 handles edge j+g; each lane owns
// 8 features [8*(lane&7)..+8) = 16B. Per 8 edges: 1 shfl + 1 dwordx4 load
// (vs R7: 4 shfl + 4 dword + 8 addr). Cross-group xor-tree at the end.
// All shfls execute with ALL lanes active, source lane always < cnt.
__global__ void k_agg(const u16* __restrict__ hin, const float* __restrict__ ss,
                      const float* __restrict__ epsp, const int* __restrict__ rowstart,
                      const int* __restrict__ esrc, u16* __restrict__ out) {
    int lane = threadIdx.x & 63;
    int wid = threadIdx.x >> 6;
    int node = blockIdx.x * 4 + wid;
    if (node >= N_NODES) return;
    int grp = lane >> 3;
    int f0 = 8 * (lane & 7);
    float acc[8] = {0.f, 0.f, 0.f, 0.f, 0.f, 0.f, 0.f, 0.f};
    int e0 = rowstart[node], e1 = rowstart[node + 1];
    for (int i = e0; i < e1; i += 64) {
        int cnt = min(e1 - i, 64);
        int src = (lane < cnt) ? esrc[i + lane] : 0;
        int j = 0;
        for (; j + 16 <= cnt; j += 16) {   // 2 loads in flight
            int a = __shfl(src, j + grp);
            int b = __shfl(src, j + 8 + grp);
            uint4 va = *(const uint4*)(hin + (size_t)a * 64 + f0);
            uint4 vb = *(const uint4*)(hin + (size_t)b * 64 + f0);
            acc[0] += bflo(va.x); acc[1] += bfhi(va.x);
            acc[2] += bflo(va.y); acc[3] += bfhi(va.y);
            acc[4] += bflo(va.z); acc[5] += bfhi(va.z);
            acc[6] += bflo(va.w); acc[7] += bfhi(va.w);
            acc[0] += bflo(vb.x); acc[1] += bfhi(vb.x);
            acc[2] += bflo(vb.y); acc[3] += bfhi(vb.y);
            acc[4] += bflo(vb.z); acc[5] += bfhi(vb.z);
            acc[6] += bflo(vb.w); acc[7] += bfhi(vb.w);
        }
        if (j + 8 <= cnt) {
            int a = __shfl(src, j + grp);
            uint4 va = *(const uint4*)(hin + (size_t)a * 64 + f0);
            acc[0] += bflo(va.x); acc[1] += bfhi(va.x);
            acc[2] += bflo(va.y); acc[3] += bfhi(va.y);
            acc[4] += bflo(va.z); acc[5] += bfhi(va.z);
            acc[6] += bflo(va.w); acc[7] += bfhi(va.w);
            j += 8;
        }
        if (j < cnt) {                      // <8 remainder: clamp src, gate adds
            int jj = j + grp;
            int a = __shfl(src, (jj < cnt) ? jj : (cnt - 1));
            uint4 va = *(const uint4*)(hin + (size_t)a * 64 + f0);
            if (jj < cnt) {
                acc[0] += bflo(va.x); acc[1] += bfhi(va.x);
                acc[2] += bflo(va.y); acc[3] += bfhi(va.y);
                acc[4] += bflo(va.z); acc[5] += bfhi(va.z);
                acc[6] += bflo(va.w); acc[7] += bfhi(va.w);
            }
        }
    }
    #pragma unroll
    for (int k = 0; k < 8; ++k) {
        acc[k] += __shfl_xor(acc[k], 8);
        acc[k] += __shfl_xor(acc[k], 16);
        acc[k] += __shfl_xor(acc[k], 32);
    }
    float epsv = 1.0f + epsp[0];
    float deg = (float)(e1 - e0);
    uint4 sb = *(const uint4*)(hin + (size_t)node * 64 + f0);
    float self[8] = {bflo(sb.x), bfhi(sb.x), bflo(sb.y), bfhi(sb.y),
                     bflo(sb.z), bfhi(sb.z), bflo(sb.w), bfhi(sb.w)};
    float4 scA = *(const float4*)(ss + f0);
    float4 scB = *(const float4*)(ss + f0 + 4);
    float4 shA = *(const float4*)(ss + 64 + f0);
    float4 shB = *(const float4*)(ss + 64 + f0 + 4);
    float sc[8] = {scA.x, scA.y, scA.z, scA.w, scB.x, scB.y, scB.z, scB.w};
    float sh[8] = {shA.x, shA.y, shA.z, shA.w, shB.x, shB.y, shB.z, shB.w};
    if (grp == 0) {
        u32 pk[4];
        #pragma unroll
        for (int k = 0; k < 4; ++k) {
            float oa = sc[2 * k] * (acc[2 * k] + epsv * self[2 * k]) +
                       (deg + epsv) * sh[2 * k];
            float ob = sc[2 * k + 1] * (acc[2 * k + 1] + epsv * self[2 * k + 1]) +
                       (deg + epsv) * sh[2 * k + 1];
            pk[k] = (u32)f2bf(oa) | ((u32)f2bf(ob) << 16);
        }
        uint4 po = make_uint4(pk[0], pk[1], pk[2], pk[3]);
        *(uint4*)(out + (size_t)node * 64 + f0) = po;
    }
}

// ---------------- fused MLP via bf16 MFMA (unchanged, passed R7) ----------------
__global__ __launch_bounds__(256) void k_mlp(
    const u16* __restrict__ A, const u16* __restrict__ Wtg,
    const float* __restrict__ b1, const float* __restrict__ b2,
    u16* __restrict__ C, float* __restrict__ partials) {
    __shared__ __align__(16) u16 Wts[9216];   // Wt1[64*72] then Wt2[64*72]
    __shared__ __align__(16) u16 Hs[64 * 72];
    __shared__ float ssum[64];
    __shared__ float ssq[64];
    int tid = threadIdx.x;
    int r0 = blockIdx.x * 64;
    {
        const int4* srcp = (const int4*)Wtg;
        int4* dstp = (int4*)Wts;
        for (int i = tid; i < 1152; i += 256) dstp[i] = srcp[i];
    }
    if (tid < 64) { ssum[tid] = 0.f; ssq[tid] = 0.f; }
    __syncthreads();
    const u16* Wt1 = Wts;
    const u16* Wt2 = Wts + 4608;

    int lane = tid & 63;
    int w = tid >> 6;
    int m = lane & 15;
    int q = lane >> 4;
    int rowg = r0 + w * 16 + m;
    int rowc = min(rowg, N_NODES - 1);

    bf16x8 a0 = *(const bf16x8*)(A + (size_t)rowc * 64 + q * 8);
    bf16x8 a1 = *(const bf16x8*)(A + (size_t)rowc * 64 + 32 + q * 8);
    f32x4 acc[4];
    #pragma unroll
    for (int c = 0; c < 4; ++c) {
        acc[c] = (f32x4){0.f, 0.f, 0.f, 0.f};
        bf16x8 bA = *(const bf16x8*)(&Wt1[(c * 16 + m) * 72 + q * 8]);
        bf16x8 bB = *(const bf16x8*)(&Wt1[(c * 16 + m) * 72 + 32 + q * 8]);
        acc[c] = __builtin_amdgcn_mfma_f32_16x16x32_bf16(a0, bA, acc[c], 0, 0, 0);
        acc[c] = __builtin_amdgcn_mfma_f32_16x16x32_bf16(a1, bB, acc[c], 0, 0, 0);
    }
    #pragma unroll
    for (int c = 0; c < 4; ++c) {
        int col = c * 16 + m;
        float bb = b1[col];
        #pragma unroll
        for (int r = 0; r < 4; ++r) {
            int rl = w * 16 + q * 4 + r;
            Hs[rl * 72 + col] = f2bf(fmaxf(acc[c][r] + bb, 0.f));
        }
    }
    bf16x8 h0 = *(const bf16x8*)(&Hs[(w * 16 + m) * 72 + q * 8]);
    bf16x8 h1 = *(const bf16x8*)(&Hs[(w * 16 + m) * 72 + 32 + q * 8]);
    f32x4 acc2[4];
    #pragma unroll
    for (int c = 0; c < 4; ++c) {
        acc2[c] = (f32x4){0.f, 0.f, 0.f, 0.f};
        bf16x8 bA = *(const bf16x8*)(&Wt2[(c * 16 + m) * 72 + q * 8]);
        bf16x8 bB = *(const bf16x8*)(&Wt2[(c * 16 + m) * 72 + 32 + q * 8]);
        acc2[c] = __builtin_amdgcn_mfma_f32_16x16x32_bf16(h0, bA, acc2[c], 0, 0, 0);
        acc2[c] = __builtin_amdgcn_mfma_f32_16x16x32_bf16(h1, bB, acc2[c], 0, 0, 0);
    }
    #pragma unroll
    for (int c = 0; c < 4; ++c) {
        int col = c * 16 + m;
        float bb = b2[col];
        float psum = 0.f, psq = 0.f;
        #pragma unroll
        for (int r = 0; r < 4; ++r) {
            int rg = r0 + w * 16 + q * 4 + r;
            if (rg < N_NODES) {
                float o = fmaxf(acc2[c][r] + bb, 0.f);
                C[(size_t)rg * 64 + col] = f2bf(o);
                psum += o;
                psq += o * o;
            }
        }
        atomicAdd(&ssum[col], psum);
        atomicAdd(&ssq[col], psq);
    }
    __syncthreads();
    if (tid < 128) {
        float v = (tid < 64) ? ssum[tid] : ssq[tid - 64];
        partials[(size_t)blockIdx.x * 128 + tid] = v;
    }
}

// ---------------- pooling + FC + log_softmax ----------------
__global__ void k_pool(const u16* __restrict__ h, const float* __restrict__ ss,
                       const int* __restrict__ gstart, const float* __restrict__ wfc,
                       const float* __restrict__ bfc, float* __restrict__ out) {
    __shared__ float smean[2][128];
    __shared__ float smax[2][128];
    __shared__ float lg[2][8];
    int tid = threadIdx.x;
    int lane = tid & 63;
    int w = tid >> 6;
    int gi = w >> 1;
    int part = w & 1;
    int gr = blockIdx.x * 2 + gi;
    int half = lane >> 5;
    int li = lane & 31;
    int f0 = 2 * li;
    float sc0 = ss[f0], sc1 = ss[f0 + 1];
    float sh0 = ss[64 + f0], sh1 = ss[64 + f0 + 1];
    int s0n = gstart[gr], s1n = gstart[gr + 1];
    int cnt = s1n - s0n;
    int mid = s0n + (cnt >> 1);
    int a = part ? mid : s0n;
    int b = part ? s1n : mid;
    float sum0 = 0.f, sum1 = 0.f, mx0 = -3.4e38f, mx1 = -3.4e38f;
    for (int n = a + half; n < b; n += 2) {
        u32 bits = *(const u32*)(h + (size_t)n * 64 + f0);
        float x0 = fmaf(bflo(bits), sc0, sh0);
        float x1 = fmaf(bfhi(bits), sc1, sh1);
        sum0 += x0; sum1 += x1;
        mx0 = fmaxf(mx0, x0); mx1 = fmaxf(mx1, x1);
    }
    sum0 += __shfl_xor(sum0, 32);
    sum1 += __shfl_xor(sum1, 32);
    mx0 = fmaxf(mx0, __shfl_xor(mx0, 32));
    mx1 = fmaxf(mx1, __shfl_xor(mx1, 32));
    if (half == 0 && part == 0) {
        smean[gi][f0] = sum0; smean[gi][f0 + 1] = sum1;
        smax[gi][f0] = mx0;   smax[gi][f0 + 1] = mx1;
    }
    __syncthreads();
    if (half == 0 && part == 1) {
        float m0 = fmaxf(smax[gi][f0], mx0), m1 = fmaxf(smax[gi][f0 + 1], mx1);
        float t0 = smean[gi][f0] + sum0, t1 = smean[gi][f0 + 1] + sum1;
        float fc = fmaxf((float)cnt, 1.f);
        smean[gi][f0] = t0 / fc;
        smean[gi][f0 + 1] = t1 / fc;
        smax[gi][f0] = (cnt > 0) ? m0 : 0.f;
        smax[gi][f0 + 1] = (cnt > 0) ? m1 : 0.f;
    }
    __syncthreads();
    if (part == 0 && lane < NCLASS) {
        float acc = bfc[lane];
        for (int j = 0; j < 64; ++j) acc = fmaf(smean[gi][j], wfc[j * NCLASS + lane], acc);
        for (int j = 0; j < 64; ++j) acc = fmaf(smax[gi][j], wfc[(64 + j) * NCLASS + lane], acc);
        lg[gi][lane] = acc;
    }
    __syncthreads();
    if (part == 0 && lane < NCLASS) {
        float mm = -3.4e38f;
        for (int c = 0; c < NCLASS; ++c) mm = fmaxf(mm, lg[gi][c]);
        float se = 0.f;
        for (int c = 0; c < NCLASS; ++c) se += expf(lg[gi][c] - mm);
        out[gr * NCLASS + lane] = lg[gi][lane] - mm - logf(se);
    }
}

// ---------------- launch ----------------

extern "C" void kernel_launch(void* const* d_in, const int* in_sizes, int n_in,
                              void* d_out, int out_size, void* d_ws, size_t ws_size,
                              hipStream_t stream) {
    const float* x = (const float*)d_in[0];
    const int* ei = (const int*)d_in[1];
    const int* batch = (const int*)d_in[2];
    const int* esrc_in = ei;
    const int* edst_in = ei + N_EDGES;

    const float* ba[4] = {(const float*)d_in[4], (const float*)d_in[8],
                          (const float*)d_in[12], (const float*)d_in[12]};
    const float* bb[4] = {(const float*)d_in[6], (const float*)d_in[10],
                          (const float*)d_in[14], (const float*)d_in[14]};
    const float* epsv[4] = {(const float*)d_in[15], (const float*)d_in[18],
                            (const float*)d_in[21], (const float*)d_in[24]};
    const float* gg[4] = {(const float*)d_in[16], (const float*)d_in[19],
                          (const float*)d_in[22], (const float*)d_in[25]};
    const float* bee[4] = {(const float*)d_in[17], (const float*)d_in[20],
                           (const float*)d_in[23], (const float*)d_in[26]};
    const float* wfc = (const float*)d_in[27];
    const float* bfc = (const float*)d_in[28];
    float* out = (float*)d_out;

    char* ws = (char*)d_ws;
    int* pairs = (int*)(ws + 0);               // 12,800,000 (dead after k_bsort)
    u16* bufA = (u16*)(ws + 0);                // alias of pairs
    int* esrc = (int*)(ws + 12800000);         // 12,800,000
    u16* xb = (u16*)(ws + 25600000);           // 12,800,000
    u16* bufB = (u16*)(ws + 38400000);         // 12,800,000
    int* rowstart = (int*)(ws + 51200000);     // 400,128
    int* blockhist = (int*)(ws + 51600128);    // 612,352 (padded)
    int* colsum = (int*)(ws + 52212480);       // 2,048
    int* bstart = (int*)(ws + 52214528);       // 2,048
    int* gstart = (int*)(ws + 52216576);       // 2,560
    float* partials = (float*)(ws + 52219136); // 800,768 (padded)
    float* ssbuf = (float*)(ws + 53019904);    // 2,560
    u16* Wtg = (u16*)(ws + 53022464);          // 55,296
    // total: 53,077,760 bytes; no memsets needed

    k_cast<<<(N_NODES * 64 / 4 + 255) / 256, 256, 0, stream>>>(x, xb);
    k_prep<<<97, 256, 0, stream>>>((const float*)d_in[3], (const float*)d_in[5],
                                   (const float*)d_in[7], (const float*)d_in[9],
                                   (const float*)d_in[11], (const float*)d_in[13],
                                   Wtg, ssbuf);
    k_hist<<<EB + NBLK_NODE, 256, 0, stream>>>(edst_in, batch, blockhist, gstart);
    k_scan_cols<<<NBUCK, 512, 0, stream>>>(blockhist, colsum);
    k_scan_b<<<1, 512, 0, stream>>>(colsum, bstart, rowstart);
    k_bscatter<<<EB, 256, 0, stream>>>(esrc_in, edst_in, bstart, blockhist, pairs);
    k_bsort<<<NBUCK, 256, 0, stream>>>(pairs, bstart, rowstart, esrc);

    const int AGG_GRID = (N_NODES + 3) / 4;
    for (int L = 0; L < 4; ++L) {
        const u16* hin = (L == 0) ? xb : bufB;
        const u16* wt = Wtg + (size_t)((L < 2) ? L : 2) * 9216;
        k_agg<<<AGG_GRID, 256, 0, stream>>>(hin, ssbuf + L * 128, epsv[L], rowstart,
                                            esrc, bufA);
        k_mlp<<<MLPG, 256, 0, stream>>>(bufA, wt, ba[L], bb[L], bufB, partials);
        k_bn<<<64, 256, 0, stream>>>(partials, gg[L], bee[L], ssbuf + (L + 1) * 128);
    }

    k_pool<<<NGRAPH / 2, 256, 0, stream>>>(bufB, ssbuf + 4 * 128, gstart, wfc, bfc, out);
}